// Round 12
// baseline (303.364 us; speedup 1.0000x reference)
//
#include <hip/hip_runtime.h>

#define N_K 20000
#define N_E 50000
#define N_U 100000
#define E_TOT 2200000
#define N_TOT 240000
// key-space (concat dst) bases
#define KB1 0
#define KB2 20000
#define KB3 40000
#define KB4 90000
#define KB5 190000
// bucket sort geometry
#define NBKT 726
#define EPB 8192
#define NBLKA 269          // ceil(E_TOT / EPB)
#define APAD 272
// fused agg+gemm block counts (16 nodes per block)
#define KN_B 1250
#define EX_B 3125
#define ST_B 6250

typedef unsigned short u16;
typedef unsigned int u32;
typedef __bf16 bf16x8 __attribute__((ext_vector_type(8)));
typedef float f32x4 __attribute__((ext_vector_type(4)));

__device__ __forceinline__ float bf2f(u16 v){
    union { u32 u; float f; } x; x.u = ((u32)v) << 16; return x.f;
}
__device__ __forceinline__ u16 f2bf(float f){
    union { float f; u32 u; } x; x.f = f;
    u32 r = x.u + 0x7FFFu + ((x.u >> 16) & 1u);
    return (u16)(r >> 16);
}
__device__ __forceinline__ float leaky_exp(float x){
    x = x >= 0.f ? x : 0.01f*x;
    return __expf(x);
}

// bucket mapping: per-range shifts, each bucket <=512 keys
__device__ __forceinline__ int bucket_of(int key){
    if (key < 20000)  return key >> 8;
    if (key < 40000)  return 79  + ((key - 20000) >> 7);
    if (key < 90000)  return 236 + ((key - 40000) >> 9);
    if (key < 190000) return 334 + ((key - 90000) >> 9);
    return 530 + ((key - 190000) >> 8);
}
__device__ __forceinline__ int local_of(int key){
    if (key < 20000)  return key & 255;
    if (key < 40000)  return (key - 20000) & 127;
    if (key < 90000)  return (key - 40000) & 511;
    if (key < 190000) return (key - 90000) & 511;
    return (key - 190000) & 255;
}
__device__ __forceinline__ void bucket_info(int b, int& kb, int& w, int& r){
    if (b < 79){       r=0; kb = b << 8;                 w = min(256, 20000  - kb); }
    else if (b < 236){ r=1; kb = 20000 + ((b-79)  << 7); w = min(128, 40000  - kb); }
    else if (b < 334){ r=2; kb = 40000 + ((b-236) << 9); w = min(512, 90000  - kb); }
    else if (b < 530){ r=3; kb = 90000 + ((b-334) << 9); w = min(512, 190000 - kb); }
    else {             r=4; kb = 190000 + ((b-530) << 8); w = min(256, 240000 - kb); }
}
__device__ __forceinline__ int edge_key(int e,
    const int* ud, const int* es, const int* ed, const int* vs, const int* vd){
    if (e < 200000)  return ud[e];
    if (e < 600000)  return 20000  + ed[e-200000];
    if (e < 1000000) return 40000  + es[e-600000];
    if (e < 1600000) return 90000  + vd[e-1000000];
    return 190000 + vs[e-1600000];
}
__device__ __forceinline__ int edge_src(int e,
    const int* us, const int* es, const int* ed, const int* vs, const int* vd){
    if (e < 200000)  return us[e];
    if (e < 600000)  return es[e-200000];
    if (e < 1000000) return ed[e-600000];
    if (e < 1600000) return vs[e-1000000];
    return vd[e-1600000];
}

// ------------------------------------------------- fused weight prep (vecs + MFMA frags)
__global__ __launch_bounds__(256) void prep_w(
    const float* W0, const float* W1, const float* W2, const float* W3, const float* W4,
    const float* a0, const float* a1, const float* a2, const float* a3, const float* a4,
    float* __restrict__ vecs, u16* __restrict__ Wf)
{
    int bid = blockIdx.x;
    if (bid < 320){
        int o = bid*4 + (threadIdx.x >> 6);
        int lane = threadIdx.x & 63;
        int which = o / 640, rem = o - which*640, g = rem >> 7, k = rem & 127;
        const float* W = g==0?W0:g==1?W1:g==2?W2:g==3?W3:W4;
        const float* a = g==0?a0:g==1?a1:g==2?a2:g==3?a3:a4;
        const float* av = a + which*128;
        int c = lane*2;
        float s = W[k*128 + c]*av[c] + W[k*128 + c + 1]*av[c+1];
        #pragma unroll
        for (int m = 32; m; m >>= 1) s += __shfl_xor(s, m);
        if (lane == 0) vecs[(which*5 + g)*128 + k] = s;
    } else {
        int t = (bid - 320)*256 + threadIdx.x;   // 0..10239
        int g = t / 2048, i = t - g*2048;
        const float* W = g==0?W0:g==1?W1:g==2?W2:g==3?W3:W4;
        int lane = i & 63, tt = i >> 6, ks = tt & 3, ct = tt >> 2;
        int kbase = ks*32 + (lane>>4)*8;
        int c = ct*16 + (lane&15);
        #pragma unroll
        for (int j = 0; j < 8; ++j)
            Wf[g*16384 + i*8 + j] = f2bf(W[(kbase+j)*128 + c]);
    }
}

// ------------------------------------------------- fused conv(f32->bf16) + row dots
template<int WBF>
__global__ __launch_bounds__(256) void conv_all(
    const float* __restrict__ kn, const float* __restrict__ exer, const float* __restrict__ stu,
    u16* __restrict__ knb, u16* __restrict__ exerb, u16* __restrict__ stub,
    const float* __restrict__ vecs,
    float* __restrict__ el1, float* __restrict__ el2, float* __restrict__ el3,
    float* __restrict__ el4, float* __restrict__ el5, float* __restrict__ erc)
{
    int w = (int)((blockIdx.x*(u32)blockDim.x + threadIdx.x) >> 6);
    int lane = threadIdx.x & 63;
    if (w >= 170000) return;
    const float* h; u16* hb; int local, nd;
    const float *v0,*v1,*v2,*v3;
    float *o0,*o1,*o2,*o3;
    if (w < 20000){
        local = w; h = kn; hb = knb; nd = 4;
        v0=vecs+0;    v1=vecs+640;  v2=vecs+768;  v3=vecs+256;
        o0=el1; o1=erc+KB1; o2=erc+KB2; o3=el3;
    } else if (w < 70000){
        local = w - 20000; h = exer; hb = exerb; nd = 4;
        v0=vecs+128;  v1=vecs+896;  v2=vecs+384;  v3=vecs+1152;
        o0=el2; o1=erc+KB3; o2=el4; o3=erc+KB5;
    } else {
        local = w - 70000; h = stu; hb = stub; nd = 2;
        v0=vecs+1024; v1=vecs+512;  v2=vecs;      v3=vecs;
        o0=erc+KB4; o1=el5; o2=nullptr; o3=nullptr;
    }
    float2 hv = *(const float2*)(h + (size_t)local*128 + lane*2);
    if (WBF)
        *(u32*)(hb + (size_t)local*128 + lane*2) = (u32)f2bf(hv.x) | ((u32)f2bf(hv.y) << 16);
    int c = lane*2;
    float d0 = hv.x*v0[c] + hv.y*v0[c+1];
    float d1 = hv.x*v1[c] + hv.y*v1[c+1];
    float d2 = hv.x*v2[c] + hv.y*v2[c+1];
    float d3 = hv.x*v3[c] + hv.y*v3[c+1];
    #pragma unroll
    for (int o = 32; o; o >>= 1){
        d0 += __shfl_xor(d0, o); d1 += __shfl_xor(d1, o);
        d2 += __shfl_xor(d2, o); d3 += __shfl_xor(d3, o);
    }
    if (lane == 0){
        o0[local] = d0; o1[local] = d1;
        if (nd == 4){ o2[local] = d2; o3[local] = d3; }
    }
}

// ------------------------------------------------- atomic-free CSR build
__global__ __launch_bounds__(256) void bkt_hist(
    const int* __restrict__ ud, const int* __restrict__ es, const int* __restrict__ ed,
    const int* __restrict__ vs, const int* __restrict__ vd, int* __restrict__ hist)
{
    __shared__ int h[NBKT];
    for (int i = threadIdx.x; i < NBKT; i += 256) h[i] = 0;
    __syncthreads();
    int base = blockIdx.x * EPB;
    #pragma unroll 4
    for (int it = 0; it < EPB/256; ++it){
        int e = base + it*256 + threadIdx.x;
        if (e < E_TOT){
            int key = edge_key(e, ud, es, ed, vs, vd);
            atomicAdd(&h[bucket_of(key)], 1);
        }
    }
    __syncthreads();
    for (int i = threadIdx.x; i < NBKT; i += 256)
        hist[i*APAD + blockIdx.x] = h[i];
}

__global__ __launch_bounds__(512) void bkt_scan1(int* __restrict__ hist, int* __restrict__ btot)
{
    __shared__ int sm[512];
    int t = threadIdx.x;
    int v = (t < NBLKA) ? hist[blockIdx.x*APAD + t] : 0;
    sm[t] = v; __syncthreads();
    #pragma unroll
    for (int d = 1; d < 512; d <<= 1){
        int x = (t >= d) ? sm[t-d] : 0;
        __syncthreads();
        sm[t] += x;
        __syncthreads();
    }
    if (t < NBLKA) hist[blockIdx.x*APAD + t] = sm[t] - v;
    if (t == 511) btot[blockIdx.x] = sm[511];
}

__global__ __launch_bounds__(1024) void bkt_scan2(const int* __restrict__ btot, int* __restrict__ bbase)
{
    __shared__ int sm[1024];
    int t = threadIdx.x;
    int v = (t < NBKT) ? btot[t] : 0;
    sm[t] = v; __syncthreads();
    #pragma unroll
    for (int d = 1; d < 1024; d <<= 1){
        int x = (t >= d) ? sm[t-d] : 0;
        __syncthreads();
        sm[t] += x;
        __syncthreads();
    }
    if (t < NBKT) bbase[t] = sm[t] - v;
}

// scatter {src|local<<17, ev} records; ev computed here (el/erc L2-hot)
__global__ __launch_bounds__(256) void bkt_scatter(
    const int* __restrict__ us, const int* __restrict__ ud,
    const int* __restrict__ es, const int* __restrict__ ed,
    const int* __restrict__ vs, const int* __restrict__ vd,
    const int* __restrict__ hist, const int* __restrict__ bbase,
    const float* __restrict__ el1, const float* __restrict__ el2,
    const float* __restrict__ el3, const float* __restrict__ el4,
    const float* __restrict__ el5, const float* __restrict__ erc,
    uint2* __restrict__ rec)
{
    __shared__ int cur[NBKT];
    for (int i = threadIdx.x; i < NBKT; i += 256)
        cur[i] = bbase[i] + hist[i*APAD + blockIdx.x];
    __syncthreads();
    int base = blockIdx.x * EPB;
    #pragma unroll 4
    for (int it = 0; it < EPB/256; ++it){
        int e = base + it*256 + threadIdx.x;
        if (e < E_TOT){
            int key = edge_key(e, ud, es, ed, vs, vd);
            int src = edge_src(e, us, es, ed, vs, vd);
            const float* el = (e < 200000) ? el1 : (e < 600000) ? el2 :
                              (e < 1000000) ? el3 : (e < 1600000) ? el4 : el5;
            float ev = leaky_exp(el[src] + erc[key]);
            int local = local_of(key);
            int pos = atomicAdd(&cur[bucket_of(key)], 1);
            rec[pos] = make_uint2((u32)src | ((u32)local << 17), __float_as_uint(ev));
        }
    }
}

// per-bucket: key hist + ev-sum -> cnt/offA (bbase + LDS scan), then place
// {src, alpha=ev/sum}. ev/local carried in rec (packed) -> no gathers here.
__global__ __launch_bounds__(512) void bkt_finalize(const uint2* __restrict__ rec,
    const int* __restrict__ bbase, const int* __restrict__ btot,
    int* __restrict__ cnt, int* __restrict__ offA, int2* __restrict__ sorted2)
{
    __shared__ int   h[512];
    __shared__ float s[512];
    __shared__ int   sm[512];
    __shared__ int   curk[512];
    int b = blockIdx.x, t = threadIdx.x;
    int kb, w, r;
    bucket_info(b, kb, w, r);
    h[t] = 0; s[t] = 0.f;
    __syncthreads();
    int start = bbase[b], n = btot[b];
    for (int i = t; i < n; i += 512){
        uint2 rc = rec[start + i];
        int local = (int)(rc.x >> 17);
        atomicAdd(&h[local], 1);
        atomicAdd(&s[local], __uint_as_float(rc.y));
    }
    __syncthreads();
    int hv = h[t];
    if (t < w) cnt[kb + t] = hv;
    sm[t] = hv; __syncthreads();
    #pragma unroll
    for (int d = 1; d < 512; d <<= 1){
        int x = (t >= d) ? sm[t-d] : 0;
        __syncthreads();
        sm[t] += x;
        __syncthreads();
    }
    int pos0 = start + sm[t] - hv;
    if (t < w) offA[kb + t] = pos0;
    curk[t] = pos0;
    __syncthreads();
    for (int i = t; i < n; i += 512){
        uint2 rc = rec[start + i];
        int local = (int)(rc.x >> 17);
        float alpha = __uint_as_float(rc.y) / s[local];
        int pos = atomicAdd(&curk[local], 1);
        sorted2[pos] = make_int2((int)(rc.x & 0x1FFFFu), __float_as_int(alpha));
    }
}

// ------------------------------------------------- fused aggregation + dual-GEMM + epilogue
// Wide-gather layout (r12): 16 lanes per edge-row (16B/lane), 4 edges per
// wave-instruction -> 4x fewer VMEM instructions. Paired rows keep 2 chunk
// chains in flight. Cross-group merge via shfl_xor(16/32).
template<int BF>
__global__ __launch_bounds__(256) void agg_gemm_epi(
    const int* __restrict__ cnt, const int* __restrict__ offA, const int2* __restrict__ sorted2,
    const void* __restrict__ hk, const void* __restrict__ he, const void* __restrict__ hs,
    const u16* __restrict__ Wf,
    const float* __restrict__ kfc2w, const float* __restrict__ kfc2b,
    const float* __restrict__ kfc3w, const float* __restrict__ kfc3b,
    const float* __restrict__ efc1w, const float* __restrict__ efc1b,
    const float* __restrict__ efc2w, const float* __restrict__ efc2b,
    float* __restrict__ out)
{
    __shared__ u16 ldsC[16*136];
    __shared__ u16 ldsD[16*136];
    __shared__ float sred2[16], sred3[16], p2s[16], p3s[16];

    int bid = blockIdx.x;
    int wave = threadIdx.x >> 6, lane = threadIdx.x & 63;
    int g = lane >> 4, s = lane & 15;
    int kind, node0, keyC, keyD;
    const void *hC, *hD, *Aseg;
    const u16 *wc, *wd;
    const float *w2, *b2, *w3, *b3;
    float* outp;
    if (bid < KN_B){
        kind=0; node0 = bid*16;
        keyC = KB1 + node0; keyD = KB2 + node0;
        hC = hk; hD = he; Aseg = hk;
        wc = Wf; wd = Wf + 16384;
        w2=kfc2w; b2=kfc2b; w3=kfc3w; b3=kfc3b;
        outp = out;
    } else if (bid < KN_B + EX_B){
        kind=0; node0 = (bid - KN_B)*16;
        keyC = KB3 + node0; keyD = KB5 + node0;
        hC = hk; hD = hs; Aseg = he;
        wc = Wf + 2*16384; wd = Wf + 4*16384;
        w2=efc1w; b2=efc1b; w3=efc2w; b3=efc2b;
        outp = out + (size_t)N_K*128;
    } else {
        kind=1; node0 = (bid - KN_B - EX_B)*16;
        keyC = KB4 + node0; keyD = 0;
        hC = he; hD = nullptr; Aseg = hs;
        wc = Wf + 3*16384; wd = nullptr;
        w2=nullptr; b2=nullptr; w3=nullptr; b3=nullptr;
        outp = out + (size_t)(N_K + N_E)*128;
    }

    // ---- aggregation into LDS: paired rows, 4-edge-wide chunks ----
    int rpw = (kind == 0) ? 8 : 4;
    for (int rr = 0; rr < rpw; rr += 2){
        int cA = wave*rpw + rr;                 // even -> pair stays in one seg
        int seg = cA >> 4, ndA = cA & 15;
        int keyA = (seg == 0 ? keyC : keyD) + ndA;
        const u16* hb = (const u16*)(seg == 0 ? hC : hD);
        const float4* hf = (const float4*)(seg == 0 ? hC : hD);
        int degA = cnt[keyA],     startA = offA[keyA];
        int degB = cnt[keyA + 1], startB = offA[keyA + 1];
        float aA8[8], aB8[8];
        #pragma unroll
        for (int k = 0; k < 8; ++k){ aA8[k] = 0.f; aB8[k] = 0.f; }

        auto chunk = [&](const int2* sp, float* acc){
            int2 w = sp[g];
            float al = __int_as_float(w.y);
            if (BF){
                uint4 hv = *(const uint4*)(hb + (size_t)w.x*128 + s*8);
                acc[0] = fmaf(al, bf2f((u16)hv.x), acc[0]);
                acc[1] = fmaf(al, bf2f((u16)(hv.x>>16)), acc[1]);
                acc[2] = fmaf(al, bf2f((u16)hv.y), acc[2]);
                acc[3] = fmaf(al, bf2f((u16)(hv.y>>16)), acc[3]);
                acc[4] = fmaf(al, bf2f((u16)hv.z), acc[4]);
                acc[5] = fmaf(al, bf2f((u16)(hv.z>>16)), acc[5]);
                acc[6] = fmaf(al, bf2f((u16)hv.w), acc[6]);
                acc[7] = fmaf(al, bf2f((u16)(hv.w>>16)), acc[7]);
            } else {
                const float4* rp = hf + (size_t)w.x*32 + s*2;
                float4 p0 = rp[0], p1 = rp[1];
                acc[0] = fmaf(al, p0.x, acc[0]); acc[1] = fmaf(al, p0.y, acc[1]);
                acc[2] = fmaf(al, p0.z, acc[2]); acc[3] = fmaf(al, p0.w, acc[3]);
                acc[4] = fmaf(al, p1.x, acc[4]); acc[5] = fmaf(al, p1.y, acc[5]);
                acc[6] = fmaf(al, p1.z, acc[6]); acc[7] = fmaf(al, p1.w, acc[7]);
            }
        };

        int iA = 0, iB = 0;
        while (iA + 4 <= degA && iB + 4 <= degB){
            chunk(sorted2 + startA + iA, aA8);
            chunk(sorted2 + startB + iB, aB8);
            iA += 4; iB += 4;
        }
        for (; iA + 4 <= degA; iA += 4) chunk(sorted2 + startA + iA, aA8);
        for (; iB + 4 <= degB; iB += 4) chunk(sorted2 + startB + iB, aB8);
        int remA = degA - iA;
        if (g < remA) chunk(sorted2 + startA + iA, aA8);   // per-group predicated tail
        int remB = degB - iB;
        if (g < remB) chunk(sorted2 + startB + iB, aB8);

        // merge the 4 lane-groups (same columns, disjoint edge subsets)
        #pragma unroll
        for (int k = 0; k < 8; ++k){
            aA8[k] += __shfl_xor(aA8[k], 16); aA8[k] += __shfl_xor(aA8[k], 32);
            aB8[k] += __shfl_xor(aB8[k], 16); aB8[k] += __shfl_xor(aB8[k], 32);
        }
        u16* ldsSeg = (seg == 0 ? ldsC : ldsD);
        if (lane < 16){
            u32 p0 = (u32)f2bf(aA8[0]) | ((u32)f2bf(aA8[1]) << 16);
            u32 p1 = (u32)f2bf(aA8[2]) | ((u32)f2bf(aA8[3]) << 16);
            u32 p2 = (u32)f2bf(aA8[4]) | ((u32)f2bf(aA8[5]) << 16);
            u32 p3 = (u32)f2bf(aA8[6]) | ((u32)f2bf(aA8[7]) << 16);
            *(uint4*)(ldsSeg + ndA*136 + lane*8) = make_uint4(p0,p1,p2,p3);
            u32 q0 = (u32)f2bf(aB8[0]) | ((u32)f2bf(aB8[1]) << 16);
            u32 q1 = (u32)f2bf(aB8[2]) | ((u32)f2bf(aB8[3]) << 16);
            u32 q2 = (u32)f2bf(aB8[4]) | ((u32)f2bf(aB8[5]) << 16);
            u32 q3 = (u32)f2bf(aB8[6]) | ((u32)f2bf(aB8[7]) << 16);
            *(uint4*)(ldsSeg + (ndA+1)*136 + lane*8) = make_uint4(q0,q1,q2,q3);
        }
    }
    if (threadIdx.x < 16){ sred2[threadIdx.x] = 0.f; sred3[threadIdx.x] = 0.f; }
    __syncthreads();

    // ---- GEMM phase: wave handles ct = 2*wave, 2*wave+1 ----
    int colb = lane & 15, rlo = (lane >> 4)*4;
    const float* Af = (const float*)Aseg;
    const u16*   Ab = (const u16*)Aseg;

    bf16x8 afC[4];
    #pragma unroll
    for (int ks = 0; ks < 4; ++ks)
        afC[ks] = *(const bf16x8*)(ldsC + (lane & 15)*136 + ks*32 + (lane >> 4)*8);
    f32x4 accC[2];
    accC[0] = (f32x4){0.f,0.f,0.f,0.f}; accC[1] = (f32x4){0.f,0.f,0.f,0.f};
    #pragma unroll
    for (int ci = 0; ci < 2; ++ci){
        int ct = wave*2 + ci;
        #pragma unroll
        for (int ks = 0; ks < 4; ++ks){
            bf16x8 bfr = *(const bf16x8*)(wc + ((ct*4+ks)*64 + lane)*8);
            accC[ci] = __builtin_amdgcn_mfma_f32_16x16x32_bf16(afC[ks], bfr, accC[ci], 0, 0, 0);
        }
    }

    if (kind == 1){
        #pragma unroll
        for (int ci = 0; ci < 2; ++ci){
            int ct = wave*2 + ci;
            #pragma unroll
            for (int j = 0; j < 4; ++j){
                size_t idx = (size_t)(node0 + rlo + j)*128 + ct*16 + colb;
                float av = BF ? bf2f(Ab[idx]) : Af[idx];
                outp[idx] = accC[ci][j] + av;
            }
        }
        return;
    }

    bf16x8 afD[4];
    #pragma unroll
    for (int ks = 0; ks < 4; ++ks)
        afD[ks] = *(const bf16x8*)(ldsD + (lane & 15)*136 + ks*32 + (lane >> 4)*8);
    f32x4 accD[2];
    accD[0] = (f32x4){0.f,0.f,0.f,0.f}; accD[1] = (f32x4){0.f,0.f,0.f,0.f};
    #pragma unroll
    for (int ci = 0; ci < 2; ++ci){
        int ct = wave*2 + ci;
        #pragma unroll
        for (int ks = 0; ks < 4; ++ks){
            bf16x8 bfr = *(const bf16x8*)(wd + ((ct*4+ks)*64 + lane)*8);
            accD[ci] = __builtin_amdgcn_mfma_f32_16x16x32_bf16(afD[ks], bfr, accD[ci], 0, 0, 0);
        }
    }

    float aA[2][4];
    float s2p[4] = {0.f,0.f,0.f,0.f}, s3p[4] = {0.f,0.f,0.f,0.f};
    #pragma unroll
    for (int ci = 0; ci < 2; ++ci){
        int ct = wave*2 + ci;
        float w2l = w2[ct*16 + colb], w2h = w2[128 + ct*16 + colb];
        float w3l = w3[ct*16 + colb], w3h = w3[128 + ct*16 + colb];
        #pragma unroll
        for (int j = 0; j < 4; ++j){
            size_t idx = (size_t)(node0 + rlo + j)*128 + ct*16 + colb;
            float av = BF ? bf2f(Ab[idx]) : Af[idx];
            aA[ci][j] = av;
            s2p[j] = fmaf(av, w2l, fmaf(accC[ci][j], w2h, s2p[j]));
            s3p[j] = fmaf(av, w3l, fmaf(accD[ci][j], w3h, s3p[j]));
        }
    }
    #pragma unroll
    for (int m = 8; m; m >>= 1)
        #pragma unroll
        for (int j = 0; j < 4; ++j){
            s2p[j] += __shfl_xor(s2p[j], m);
            s3p[j] += __shfl_xor(s3p[j], m);
        }
    if (colb == 0){
        #pragma unroll
        for (int j = 0; j < 4; ++j){
            atomicAdd(&sred2[rlo + j], s2p[j]);
            atomicAdd(&sred3[rlo + j], s3p[j]);
        }
    }
    __syncthreads();
    if (threadIdx.x < 16){
        float s2 = sred2[threadIdx.x] + b2[0];
        float s3 = sred3[threadIdx.x] + b3[0];
        float mx = fmaxf(s2, s3);
        float e2 = __expf(s2 - mx), e3 = __expf(s3 - mx);
        float inv = 1.f/(e2 + e3);
        p2s[threadIdx.x] = e2*inv;
        p3s[threadIdx.x] = e3*inv;
    }
    __syncthreads();
    #pragma unroll
    for (int ci = 0; ci < 2; ++ci){
        int ct = wave*2 + ci;
        #pragma unroll
        for (int j = 0; j < 4; ++j){
            int row = rlo + j;
            size_t idx = (size_t)(node0 + row)*128 + ct*16 + colb;
            outp[idx] = aA[ci][j] + p2s[row]*accC[ci][j] + p3s[row]*accD[ci][j];
        }
    }
}

extern "C" void kernel_launch(void* const* d_in, const int* in_sizes, int n_in,
                              void* d_out, int out_size, void* d_ws, size_t ws_size,
                              hipStream_t stream)
{
    (void)in_sizes; (void)n_in; (void)out_size;
    const float* kn   = (const float*)d_in[0];
    const float* exer = (const float*)d_in[1];
    const float* stu  = (const float*)d_in[2];
    const int* und_src = (const int*)d_in[3];
    const int* und_dst = (const int*)d_in[4];
    const int* ek_src  = (const int*)d_in[5];
    const int* ek_dst  = (const int*)d_in[6];
    const int* eu_src  = (const int*)d_in[7];
    const int* eu_dst  = (const int*)d_in[8];
    const float* W_und = (const float*)d_in[9];  const float* a_und = (const float*)d_in[10];
    const float* W_ek  = (const float*)d_in[11]; const float* a_ek  = (const float*)d_in[12];
    const float* W_ke  = (const float*)d_in[13]; const float* a_ke  = (const float*)d_in[14];
    const float* W_eu  = (const float*)d_in[15]; const float* a_eu  = (const float*)d_in[16];
    const float* W_ue  = (const float*)d_in[17]; const float* a_ue  = (const float*)d_in[18];
    const float* kfc2w = (const float*)d_in[19]; const float* kfc2b = (const float*)d_in[20];
    const float* kfc3w = (const float*)d_in[21]; const float* kfc3b = (const float*)d_in[22];
    const float* efc1w = (const float*)d_in[23]; const float* efc1b = (const float*)d_in[24];
    const float* efc2w = (const float*)d_in[25]; const float* efc2b = (const float*)d_in[26];

    char* base = (char*)d_ws;
    size_t off_b = 0;
    auto alloc = [&](size_t bytes)->char*{
        char* p = base + off_b;
        off_b += (bytes + 255) & ~(size_t)255;
        return p;
    };
    float* vecs = (float*)alloc(1280*4);
    u16*   Wf   = (u16*)  alloc(5*16384*2);
    float* el1 = (float*)alloc(N_K*4);
    float* el2 = (float*)alloc(N_E*4);
    float* el3 = (float*)alloc(N_K*4);
    float* el4 = (float*)alloc(N_E*4);
    float* el5 = (float*)alloc(N_U*4);
    float* erc = (float*)alloc((size_t)N_TOT*4);
    int* cnt  = (int*)alloc((size_t)N_TOT*4);
    int* offA = (int*)alloc((size_t)N_TOT*4);
    int* btot = (int*)alloc(NBKT*4);
    int* bbase= (int*)alloc(NBKT*4);
    int* hist = (int*)alloc((size_t)NBKT*APAD*4);
    uint2* rec = (uint2*)alloc((size_t)E_TOT*8);     // {src|local<<17, ev}
    int2* sorted2 = (int2*)alloc((size_t)E_TOT*8);   // {src, alpha}
    u16* knb   = (u16*)alloc((size_t)N_K*128*2);
    u16* exerb = (u16*)alloc((size_t)N_E*128*2);
    u16* stub  = (u16*)alloc((size_t)N_U*128*2);
    size_t need_bf = off_b;
    bool useBF = (ws_size >= need_bf);
    float* out = (float*)d_out;

    prep_w<<<360,256,0,stream>>>(W_und,W_ek,W_ke,W_eu,W_ue, a_und,a_ek,a_ke,a_eu,a_ue, vecs, Wf);

    if (useBF)
        conv_all<1><<<(170000+3)/4,256,0,stream>>>(kn, exer, stu, knb, exerb, stub, vecs,
                                                   el1, el2, el3, el4, el5, erc);
    else
        conv_all<0><<<(170000+3)/4,256,0,stream>>>(kn, exer, stu, knb, exerb, stub, vecs,
                                                   el1, el2, el3, el4, el5, erc);

    bkt_hist<<<NBLKA,256,0,stream>>>(und_dst, ek_src, ek_dst, eu_src, eu_dst, hist);
    bkt_scan1<<<NBKT,512,0,stream>>>(hist, btot);
    bkt_scan2<<<1,1024,0,stream>>>(btot, bbase);
    bkt_scatter<<<NBLKA,256,0,stream>>>(und_src, und_dst, ek_src, ek_dst, eu_src, eu_dst,
                                        hist, bbase,
                                        el1, el2, el3, el4, el5, erc, rec);
    bkt_finalize<<<NBKT,512,0,stream>>>(rec, bbase, btot, cnt, offA, sorted2);

    if (useBF){
        agg_gemm_epi<1><<<KN_B+EX_B+ST_B,256,0,stream>>>(cnt, offA, sorted2,
            knb, exerb, stub, Wf,
            kfc2w,kfc2b,kfc3w,kfc3b, efc1w,efc1b,efc2w,efc2b, out);
    } else {
        agg_gemm_epi<0><<<KN_B+EX_B+ST_B,256,0,stream>>>(cnt, offA, sorted2,
            kn, exer, stu, Wf,
            kfc2w,kfc2b,kfc3w,kfc3b, efc1w,efc1b,efc2w,efc2b, out);
    }
}

// Round 13
// 290.855 us; speedup vs baseline: 1.0430x; 1.0430x over previous
//
#include <hip/hip_runtime.h>

#define N_K 20000
#define N_E 50000
#define N_U 100000
#define E_TOT 2200000
#define N_TOT 240000
// key-space (concat dst) bases
#define KB1 0
#define KB2 20000
#define KB3 40000
#define KB4 90000
#define KB5 190000
// bucket sort geometry
#define NBKT 726
#define EPB 8192
#define NBLKA 269          // ceil(E_TOT / EPB)
#define APAD 272
// fused agg+gemm block counts (16 nodes per block)
#define KN_B 1250
#define EX_B 3125
#define ST_B 6250

typedef unsigned short u16;
typedef unsigned int u32;
typedef __bf16 bf16x8 __attribute__((ext_vector_type(8)));
typedef float f32x4 __attribute__((ext_vector_type(4)));

__device__ __forceinline__ float bf2f(u16 v){
    union { u32 u; float f; } x; x.u = ((u32)v) << 16; return x.f;
}
__device__ __forceinline__ u16 f2bf(float f){
    union { float f; u32 u; } x; x.f = f;
    u32 r = x.u + 0x7FFFu + ((x.u >> 16) & 1u);
    return (u16)(r >> 16);
}
__device__ __forceinline__ float leaky_exp(float x){
    x = x >= 0.f ? x : 0.01f*x;
    return __expf(x);
}

// bucket mapping: per-range shifts, each bucket <=512 keys
__device__ __forceinline__ int bucket_of(int key){
    if (key < 20000)  return key >> 8;
    if (key < 40000)  return 79  + ((key - 20000) >> 7);
    if (key < 90000)  return 236 + ((key - 40000) >> 9);
    if (key < 190000) return 334 + ((key - 90000) >> 9);
    return 530 + ((key - 190000) >> 8);
}
__device__ __forceinline__ void bucket_info(int b, int& kb, int& w, int& r){
    if (b < 79){       r=0; kb = b << 8;                 w = min(256, 20000  - kb); }
    else if (b < 236){ r=1; kb = 20000 + ((b-79)  << 7); w = min(128, 40000  - kb); }
    else if (b < 334){ r=2; kb = 40000 + ((b-236) << 9); w = min(512, 90000  - kb); }
    else if (b < 530){ r=3; kb = 90000 + ((b-334) << 9); w = min(512, 190000 - kb); }
    else {             r=4; kb = 190000 + ((b-530) << 8); w = min(256, 240000 - kb); }
}
__device__ __forceinline__ int edge_key(int e,
    const int* ud, const int* es, const int* ed, const int* vs, const int* vd){
    if (e < 200000)  return ud[e];
    if (e < 600000)  return 20000  + ed[e-200000];
    if (e < 1000000) return 40000  + es[e-600000];
    if (e < 1600000) return 90000  + vd[e-1000000];
    return 190000 + vs[e-1600000];
}
__device__ __forceinline__ int edge_src(int e,
    const int* us, const int* es, const int* ed, const int* vs, const int* vd){
    if (e < 200000)  return us[e];
    if (e < 600000)  return es[e-200000];
    if (e < 1000000) return ed[e-600000];
    if (e < 1600000) return vs[e-1000000];
    return vd[e-1600000];
}

// ------------------------------------------------- fused weight prep (vecs + MFMA frags)
__global__ __launch_bounds__(256) void prep_w(
    const float* W0, const float* W1, const float* W2, const float* W3, const float* W4,
    const float* a0, const float* a1, const float* a2, const float* a3, const float* a4,
    float* __restrict__ vecs, u16* __restrict__ Wf)
{
    int bid = blockIdx.x;
    if (bid < 320){
        int o = bid*4 + (threadIdx.x >> 6);
        int lane = threadIdx.x & 63;
        int which = o / 640, rem = o - which*640, g = rem >> 7, k = rem & 127;
        const float* W = g==0?W0:g==1?W1:g==2?W2:g==3?W3:W4;
        const float* a = g==0?a0:g==1?a1:g==2?a2:g==3?a3:a4;
        const float* av = a + which*128;
        int c = lane*2;
        float s = W[k*128 + c]*av[c] + W[k*128 + c + 1]*av[c+1];
        #pragma unroll
        for (int m = 32; m; m >>= 1) s += __shfl_xor(s, m);
        if (lane == 0) vecs[(which*5 + g)*128 + k] = s;
    } else {
        int t = (bid - 320)*256 + threadIdx.x;   // 0..10239
        int g = t / 2048, i = t - g*2048;
        const float* W = g==0?W0:g==1?W1:g==2?W2:g==3?W3:W4;
        int lane = i & 63, tt = i >> 6, ks = tt & 3, ct = tt >> 2;
        int kbase = ks*32 + (lane>>4)*8;
        int c = ct*16 + (lane&15);
        #pragma unroll
        for (int j = 0; j < 8; ++j)
            Wf[g*16384 + i*8 + j] = f2bf(W[(kbase+j)*128 + c]);
    }
}

// ------------------------------------------------- fused conv(f32->bf16) + row dots
template<int WBF>
__global__ __launch_bounds__(256) void conv_all(
    const float* __restrict__ kn, const float* __restrict__ exer, const float* __restrict__ stu,
    u16* __restrict__ knb, u16* __restrict__ exerb, u16* __restrict__ stub,
    const float* __restrict__ vecs,
    float* __restrict__ el1, float* __restrict__ el2, float* __restrict__ el3,
    float* __restrict__ el4, float* __restrict__ el5, float* __restrict__ erc)
{
    int w = (int)((blockIdx.x*(u32)blockDim.x + threadIdx.x) >> 6);
    int lane = threadIdx.x & 63;
    if (w >= 170000) return;
    const float* h; u16* hb; int local, nd;
    const float *v0,*v1,*v2,*v3;
    float *o0,*o1,*o2,*o3;
    if (w < 20000){
        local = w; h = kn; hb = knb; nd = 4;
        v0=vecs+0;    v1=vecs+640;  v2=vecs+768;  v3=vecs+256;
        o0=el1; o1=erc+KB1; o2=erc+KB2; o3=el3;
    } else if (w < 70000){
        local = w - 20000; h = exer; hb = exerb; nd = 4;
        v0=vecs+128;  v1=vecs+896;  v2=vecs+384;  v3=vecs+1152;
        o0=el2; o1=erc+KB3; o2=el4; o3=erc+KB5;
    } else {
        local = w - 70000; h = stu; hb = stub; nd = 2;
        v0=vecs+1024; v1=vecs+512;  v2=vecs;      v3=vecs;
        o0=erc+KB4; o1=el5; o2=nullptr; o3=nullptr;
    }
    float2 hv = *(const float2*)(h + (size_t)local*128 + lane*2);
    if (WBF)
        *(u32*)(hb + (size_t)local*128 + lane*2) = (u32)f2bf(hv.x) | ((u32)f2bf(hv.y) << 16);
    int c = lane*2;
    float d0 = hv.x*v0[c] + hv.y*v0[c+1];
    float d1 = hv.x*v1[c] + hv.y*v1[c+1];
    float d2 = hv.x*v2[c] + hv.y*v2[c+1];
    float d3 = hv.x*v3[c] + hv.y*v3[c+1];
    #pragma unroll
    for (int o = 32; o; o >>= 1){
        d0 += __shfl_xor(d0, o); d1 += __shfl_xor(d1, o);
        d2 += __shfl_xor(d2, o); d3 += __shfl_xor(d3, o);
    }
    if (lane == 0){
        o0[local] = d0; o1[local] = d1;
        if (nd == 4){ o2[local] = d2; o3[local] = d3; }
    }
}

// ------------------------------------------------- atomic-free CSR build
__global__ __launch_bounds__(256) void bkt_hist(
    const int* __restrict__ ud, const int* __restrict__ es, const int* __restrict__ ed,
    const int* __restrict__ vs, const int* __restrict__ vd, int* __restrict__ hist)
{
    __shared__ int h[NBKT];
    for (int i = threadIdx.x; i < NBKT; i += 256) h[i] = 0;
    __syncthreads();
    int base = blockIdx.x * EPB;
    #pragma unroll 4
    for (int it = 0; it < EPB/256; ++it){
        int e = base + it*256 + threadIdx.x;
        if (e < E_TOT){
            int key = edge_key(e, ud, es, ed, vs, vd);
            atomicAdd(&h[bucket_of(key)], 1);
        }
    }
    __syncthreads();
    for (int i = threadIdx.x; i < NBKT; i += 256)
        hist[i*APAD + blockIdx.x] = h[i];
}

__global__ __launch_bounds__(512) void bkt_scan1(int* __restrict__ hist, int* __restrict__ btot)
{
    __shared__ int sm[512];
    int t = threadIdx.x;
    int v = (t < NBLKA) ? hist[blockIdx.x*APAD + t] : 0;
    sm[t] = v; __syncthreads();
    #pragma unroll
    for (int d = 1; d < 512; d <<= 1){
        int x = (t >= d) ? sm[t-d] : 0;
        __syncthreads();
        sm[t] += x;
        __syncthreads();
    }
    if (t < NBLKA) hist[blockIdx.x*APAD + t] = sm[t] - v;
    if (t == 511) btot[blockIdx.x] = sm[511];
}

__global__ __launch_bounds__(1024) void bkt_scan2(const int* __restrict__ btot, int* __restrict__ bbase)
{
    __shared__ int sm[1024];
    int t = threadIdx.x;
    int v = (t < NBKT) ? btot[t] : 0;
    sm[t] = v; __syncthreads();
    #pragma unroll
    for (int d = 1; d < 1024; d <<= 1){
        int x = (t >= d) ? sm[t-d] : 0;
        __syncthreads();
        sm[t] += x;
        __syncthreads();
    }
    if (t < NBKT) bbase[t] = sm[t] - v;
}

// scatter {src, key} records; LDS cursors only (r11 version — r12's in-scatter
// ev compute was a −30 µs regression: 269 blocks = 4 waves/CU can't hide the
// random el/erc gather latency)
__global__ __launch_bounds__(256) void bkt_scatter(
    const int* __restrict__ us, const int* __restrict__ ud,
    const int* __restrict__ es, const int* __restrict__ ed,
    const int* __restrict__ vs, const int* __restrict__ vd,
    const int* __restrict__ hist, const int* __restrict__ bbase,
    uint2* __restrict__ rec)
{
    __shared__ int cur[NBKT];
    for (int i = threadIdx.x; i < NBKT; i += 256)
        cur[i] = bbase[i] + hist[i*APAD + blockIdx.x];
    __syncthreads();
    int base = blockIdx.x * EPB;
    #pragma unroll 4
    for (int it = 0; it < EPB/256; ++it){
        int e = base + it*256 + threadIdx.x;
        if (e < E_TOT){
            int key = edge_key(e, ud, es, ed, vs, vd);
            int src = edge_src(e, us, es, ed, vs, vd);
            int pos = atomicAdd(&cur[bucket_of(key)], 1);
            rec[pos] = make_uint2((u32)src, (u32)key);
        }
    }
}

// per-bucket: key hist + ev-sum -> cnt/offA (bbase + LDS scan), then place
// {src, alpha=ev/sum}. ev computed here (726x512 threads hide gather latency);
// cached in evb so pass 2 skips the el re-gather + exp.
__global__ __launch_bounds__(512) void bkt_finalize(const uint2* __restrict__ rec,
    const int* __restrict__ bbase, const int* __restrict__ btot,
    const float* __restrict__ erc,
    const float* __restrict__ el1, const float* __restrict__ el2,
    const float* __restrict__ el3, const float* __restrict__ el4,
    const float* __restrict__ el5, float* __restrict__ evb,
    int* __restrict__ cnt, int* __restrict__ offA, int2* __restrict__ sorted2)
{
    __shared__ int   h[512];
    __shared__ float s[512];
    __shared__ float ercs[512];
    __shared__ int   sm[512];
    __shared__ int   curk[512];
    int b = blockIdx.x, t = threadIdx.x;
    int kb, w, r;
    bucket_info(b, kb, w, r);
    h[t] = 0; s[t] = 0.f;
    if (t < w) ercs[t] = erc[kb + t];
    __syncthreads();
    const float* el = r==0?el1 : r==1?el2 : r==2?el3 : r==3?el4 : el5;
    int start = bbase[b], n = btot[b];
    for (int i = t; i < n; i += 512){
        uint2 rc = rec[start + i];
        int local = (int)rc.y - kb;
        float ev = leaky_exp(el[rc.x] + ercs[local]);
        evb[start + i] = ev;
        atomicAdd(&h[local], 1);
        atomicAdd(&s[local], ev);
    }
    __syncthreads();
    int hv = h[t];
    if (t < w) cnt[kb + t] = hv;
    sm[t] = hv; __syncthreads();
    #pragma unroll
    for (int d = 1; d < 512; d <<= 1){
        int x = (t >= d) ? sm[t-d] : 0;
        __syncthreads();
        sm[t] += x;
        __syncthreads();
    }
    int pos0 = start + sm[t] - hv;
    if (t < w) offA[kb + t] = pos0;
    curk[t] = pos0;
    __syncthreads();
    for (int i = t; i < n; i += 512){
        uint2 rc = rec[start + i];
        int local = (int)rc.y - kb;
        float alpha = evb[start + i] / s[local];
        int pos = atomicAdd(&curk[local], 1);
        sorted2[pos] = make_int2((int)rc.x, __float_as_int(alpha));
    }
}

// ------------------------------------------------- fused aggregation + dual-GEMM + epilogue
// Wide-gather layout (r12): 16 lanes per edge-row (16B/lane), 4 edges per
// wave-instruction. r13: 2-deep chunk pipeline per stream -> 4 gather
// instructions in flight per wave. Cross-group merge via shfl_xor(16/32).
template<int BF>
__global__ __launch_bounds__(256) void agg_gemm_epi(
    const int* __restrict__ cnt, const int* __restrict__ offA, const int2* __restrict__ sorted2,
    const void* __restrict__ hk, const void* __restrict__ he, const void* __restrict__ hs,
    const u16* __restrict__ Wf,
    const float* __restrict__ kfc2w, const float* __restrict__ kfc2b,
    const float* __restrict__ kfc3w, const float* __restrict__ kfc3b,
    const float* __restrict__ efc1w, const float* __restrict__ efc1b,
    const float* __restrict__ efc2w, const float* __restrict__ efc2b,
    float* __restrict__ out)
{
    __shared__ u16 ldsC[16*136];
    __shared__ u16 ldsD[16*136];
    __shared__ float sred2[16], sred3[16], p2s[16], p3s[16];

    int bid = blockIdx.x;
    int wave = threadIdx.x >> 6, lane = threadIdx.x & 63;
    int g = lane >> 4, s = lane & 15;
    int kind, node0, keyC, keyD;
    const void *hC, *hD, *Aseg;
    const u16 *wc, *wd;
    const float *w2, *b2, *w3, *b3;
    float* outp;
    if (bid < KN_B){
        kind=0; node0 = bid*16;
        keyC = KB1 + node0; keyD = KB2 + node0;
        hC = hk; hD = he; Aseg = hk;
        wc = Wf; wd = Wf + 16384;
        w2=kfc2w; b2=kfc2b; w3=kfc3w; b3=kfc3b;
        outp = out;
    } else if (bid < KN_B + EX_B){
        kind=0; node0 = (bid - KN_B)*16;
        keyC = KB3 + node0; keyD = KB5 + node0;
        hC = hk; hD = hs; Aseg = he;
        wc = Wf + 2*16384; wd = Wf + 4*16384;
        w2=efc1w; b2=efc1b; w3=efc2w; b3=efc2b;
        outp = out + (size_t)N_K*128;
    } else {
        kind=1; node0 = (bid - KN_B - EX_B)*16;
        keyC = KB4 + node0; keyD = 0;
        hC = he; hD = nullptr; Aseg = hs;
        wc = Wf + 3*16384; wd = nullptr;
        w2=nullptr; b2=nullptr; w3=nullptr; b3=nullptr;
        outp = out + (size_t)(N_K + N_E)*128;
    }

    // ---- aggregation into LDS: paired rows, 4-edge-wide chunks, 2-deep ----
    int rpw = (kind == 0) ? 8 : 4;
    for (int rr = 0; rr < rpw; rr += 2){
        int cA = wave*rpw + rr;                 // even -> pair stays in one seg
        int seg = cA >> 4, ndA = cA & 15;
        int keyA = (seg == 0 ? keyC : keyD) + ndA;
        const u16* hb = (const u16*)(seg == 0 ? hC : hD);
        const float4* hf = (const float4*)(seg == 0 ? hC : hD);
        int degA = cnt[keyA],     startA = offA[keyA];
        int degB = cnt[keyA + 1], startB = offA[keyA + 1];
        float aA8[8], aB8[8];
        #pragma unroll
        for (int k = 0; k < 8; ++k){ aA8[k] = 0.f; aB8[k] = 0.f; }

        auto chunk = [&](const int2* sp, float* acc){
            int2 w = sp[g];
            float al = __int_as_float(w.y);
            if (BF){
                uint4 hv = *(const uint4*)(hb + (size_t)w.x*128 + s*8);
                acc[0] = fmaf(al, bf2f((u16)hv.x), acc[0]);
                acc[1] = fmaf(al, bf2f((u16)(hv.x>>16)), acc[1]);
                acc[2] = fmaf(al, bf2f((u16)hv.y), acc[2]);
                acc[3] = fmaf(al, bf2f((u16)(hv.y>>16)), acc[3]);
                acc[4] = fmaf(al, bf2f((u16)hv.z), acc[4]);
                acc[5] = fmaf(al, bf2f((u16)(hv.z>>16)), acc[5]);
                acc[6] = fmaf(al, bf2f((u16)hv.w), acc[6]);
                acc[7] = fmaf(al, bf2f((u16)(hv.w>>16)), acc[7]);
            } else {
                const float4* rp = hf + (size_t)w.x*32 + s*2;
                float4 p0 = rp[0], p1 = rp[1];
                acc[0] = fmaf(al, p0.x, acc[0]); acc[1] = fmaf(al, p0.y, acc[1]);
                acc[2] = fmaf(al, p0.z, acc[2]); acc[3] = fmaf(al, p0.w, acc[3]);
                acc[4] = fmaf(al, p1.x, acc[4]); acc[5] = fmaf(al, p1.y, acc[5]);
                acc[6] = fmaf(al, p1.z, acc[6]); acc[7] = fmaf(al, p1.w, acc[7]);
            }
        };

        int iA = 0, iB = 0;
        // 2-deep per stream: 4 independent gather instructions in flight
        while (iA + 8 <= degA && iB + 8 <= degB){
            chunk(sorted2 + startA + iA,     aA8);
            chunk(sorted2 + startB + iB,     aB8);
            chunk(sorted2 + startA + iA + 4, aA8);
            chunk(sorted2 + startB + iB + 4, aB8);
            iA += 8; iB += 8;
        }
        while (iA + 4 <= degA && iB + 4 <= degB){
            chunk(sorted2 + startA + iA, aA8);
            chunk(sorted2 + startB + iB, aB8);
            iA += 4; iB += 4;
        }
        for (; iA + 4 <= degA; iA += 4) chunk(sorted2 + startA + iA, aA8);
        for (; iB + 4 <= degB; iB += 4) chunk(sorted2 + startB + iB, aB8);
        int remA = degA - iA;
        if (g < remA) chunk(sorted2 + startA + iA, aA8);   // per-group predicated tail
        int remB = degB - iB;
        if (g < remB) chunk(sorted2 + startB + iB, aB8);

        // merge the 4 lane-groups (same columns, disjoint edge subsets)
        #pragma unroll
        for (int k = 0; k < 8; ++k){
            aA8[k] += __shfl_xor(aA8[k], 16); aA8[k] += __shfl_xor(aA8[k], 32);
            aB8[k] += __shfl_xor(aB8[k], 16); aB8[k] += __shfl_xor(aB8[k], 32);
        }
        u16* ldsSeg = (seg == 0 ? ldsC : ldsD);
        if (lane < 16){
            u32 p0 = (u32)f2bf(aA8[0]) | ((u32)f2bf(aA8[1]) << 16);
            u32 p1 = (u32)f2bf(aA8[2]) | ((u32)f2bf(aA8[3]) << 16);
            u32 p2 = (u32)f2bf(aA8[4]) | ((u32)f2bf(aA8[5]) << 16);
            u32 p3 = (u32)f2bf(aA8[6]) | ((u32)f2bf(aA8[7]) << 16);
            *(uint4*)(ldsSeg + ndA*136 + lane*8) = make_uint4(p0,p1,p2,p3);
            u32 q0 = (u32)f2bf(aB8[0]) | ((u32)f2bf(aB8[1]) << 16);
            u32 q1 = (u32)f2bf(aB8[2]) | ((u32)f2bf(aB8[3]) << 16);
            u32 q2 = (u32)f2bf(aB8[4]) | ((u32)f2bf(aB8[5]) << 16);
            u32 q3 = (u32)f2bf(aB8[6]) | ((u32)f2bf(aB8[7]) << 16);
            *(uint4*)(ldsSeg + (ndA+1)*136 + lane*8) = make_uint4(q0,q1,q2,q3);
        }
    }
    if (threadIdx.x < 16){ sred2[threadIdx.x] = 0.f; sred3[threadIdx.x] = 0.f; }
    __syncthreads();

    // ---- GEMM phase: wave handles ct = 2*wave, 2*wave+1 ----
    int colb = lane & 15, rlo = (lane >> 4)*4;
    const float* Af = (const float*)Aseg;
    const u16*   Ab = (const u16*)Aseg;

    bf16x8 afC[4];
    #pragma unroll
    for (int ks = 0; ks < 4; ++ks)
        afC[ks] = *(const bf16x8*)(ldsC + (lane & 15)*136 + ks*32 + (lane >> 4)*8);
    f32x4 accC[2];
    accC[0] = (f32x4){0.f,0.f,0.f,0.f}; accC[1] = (f32x4){0.f,0.f,0.f,0.f};
    #pragma unroll
    for (int ci = 0; ci < 2; ++ci){
        int ct = wave*2 + ci;
        #pragma unroll
        for (int ks = 0; ks < 4; ++ks){
            bf16x8 bfr = *(const bf16x8*)(wc + ((ct*4+ks)*64 + lane)*8);
            accC[ci] = __builtin_amdgcn_mfma_f32_16x16x32_bf16(afC[ks], bfr, accC[ci], 0, 0, 0);
        }
    }

    if (kind == 1){
        #pragma unroll
        for (int ci = 0; ci < 2; ++ci){
            int ct = wave*2 + ci;
            #pragma unroll
            for (int j = 0; j < 4; ++j){
                size_t idx = (size_t)(node0 + rlo + j)*128 + ct*16 + colb;
                float av = BF ? bf2f(Ab[idx]) : Af[idx];
                outp[idx] = accC[ci][j] + av;
            }
        }
        return;
    }

    bf16x8 afD[4];
    #pragma unroll
    for (int ks = 0; ks < 4; ++ks)
        afD[ks] = *(const bf16x8*)(ldsD + (lane & 15)*136 + ks*32 + (lane >> 4)*8);
    f32x4 accD[2];
    accD[0] = (f32x4){0.f,0.f,0.f,0.f}; accD[1] = (f32x4){0.f,0.f,0.f,0.f};
    #pragma unroll
    for (int ci = 0; ci < 2; ++ci){
        int ct = wave*2 + ci;
        #pragma unroll
        for (int ks = 0; ks < 4; ++ks){
            bf16x8 bfr = *(const bf16x8*)(wd + ((ct*4+ks)*64 + lane)*8);
            accD[ci] = __builtin_amdgcn_mfma_f32_16x16x32_bf16(afD[ks], bfr, accD[ci], 0, 0, 0);
        }
    }

    float aA[2][4];
    float s2p[4] = {0.f,0.f,0.f,0.f}, s3p[4] = {0.f,0.f,0.f,0.f};
    #pragma unroll
    for (int ci = 0; ci < 2; ++ci){
        int ct = wave*2 + ci;
        float w2l = w2[ct*16 + colb], w2h = w2[128 + ct*16 + colb];
        float w3l = w3[ct*16 + colb], w3h = w3[128 + ct*16 + colb];
        #pragma unroll
        for (int j = 0; j < 4; ++j){
            size_t idx = (size_t)(node0 + rlo + j)*128 + ct*16 + colb;
            float av = BF ? bf2f(Ab[idx]) : Af[idx];
            aA[ci][j] = av;
            s2p[j] = fmaf(av, w2l, fmaf(accC[ci][j], w2h, s2p[j]));
            s3p[j] = fmaf(av, w3l, fmaf(accD[ci][j], w3h, s3p[j]));
        }
    }
    #pragma unroll
    for (int m = 8; m; m >>= 1)
        #pragma unroll
        for (int j = 0; j < 4; ++j){
            s2p[j] += __shfl_xor(s2p[j], m);
            s3p[j] += __shfl_xor(s3p[j], m);
        }
    if (colb == 0){
        #pragma unroll
        for (int j = 0; j < 4; ++j){
            atomicAdd(&sred2[rlo + j], s2p[j]);
            atomicAdd(&sred3[rlo + j], s3p[j]);
        }
    }
    __syncthreads();
    if (threadIdx.x < 16){
        float s2 = sred2[threadIdx.x] + b2[0];
        float s3 = sred3[threadIdx.x] + b3[0];
        float mx = fmaxf(s2, s3);
        float e2 = __expf(s2 - mx), e3 = __expf(s3 - mx);
        float inv = 1.f/(e2 + e3);
        p2s[threadIdx.x] = e2*inv;
        p3s[threadIdx.x] = e3*inv;
    }
    __syncthreads();
    #pragma unroll
    for (int ci = 0; ci < 2; ++ci){
        int ct = wave*2 + ci;
        #pragma unroll
        for (int j = 0; j < 4; ++j){
            int row = rlo + j;
            size_t idx = (size_t)(node0 + row)*128 + ct*16 + colb;
            outp[idx] = aA[ci][j] + p2s[row]*accC[ci][j] + p3s[row]*accD[ci][j];
        }
    }
}

extern "C" void kernel_launch(void* const* d_in, const int* in_sizes, int n_in,
                              void* d_out, int out_size, void* d_ws, size_t ws_size,
                              hipStream_t stream)
{
    (void)in_sizes; (void)n_in; (void)out_size;
    const float* kn   = (const float*)d_in[0];
    const float* exer = (const float*)d_in[1];
    const float* stu  = (const float*)d_in[2];
    const int* und_src = (const int*)d_in[3];
    const int* und_dst = (const int*)d_in[4];
    const int* ek_src  = (const int*)d_in[5];
    const int* ek_dst  = (const int*)d_in[6];
    const int* eu_src  = (const int*)d_in[7];
    const int* eu_dst  = (const int*)d_in[8];
    const float* W_und = (const float*)d_in[9];  const float* a_und = (const float*)d_in[10];
    const float* W_ek  = (const float*)d_in[11]; const float* a_ek  = (const float*)d_in[12];
    const float* W_ke  = (const float*)d_in[13]; const float* a_ke  = (const float*)d_in[14];
    const float* W_eu  = (const float*)d_in[15]; const float* a_eu  = (const float*)d_in[16];
    const float* W_ue  = (const float*)d_in[17]; const float* a_ue  = (const float*)d_in[18];
    const float* kfc2w = (const float*)d_in[19]; const float* kfc2b = (const float*)d_in[20];
    const float* kfc3w = (const float*)d_in[21]; const float* kfc3b = (const float*)d_in[22];
    const float* efc1w = (const float*)d_in[23]; const float* efc1b = (const float*)d_in[24];
    const float* efc2w = (const float*)d_in[25]; const float* efc2b = (const float*)d_in[26];

    char* base = (char*)d_ws;
    size_t off_b = 0;
    auto alloc = [&](size_t bytes)->char*{
        char* p = base + off_b;
        off_b += (bytes + 255) & ~(size_t)255;
        return p;
    };
    float* vecs = (float*)alloc(1280*4);
    u16*   Wf   = (u16*)  alloc(5*16384*2);
    float* el1 = (float*)alloc(N_K*4);
    float* el2 = (float*)alloc(N_E*4);
    float* el3 = (float*)alloc(N_K*4);
    float* el4 = (float*)alloc(N_E*4);
    float* el5 = (float*)alloc(N_U*4);
    float* erc = (float*)alloc((size_t)N_TOT*4);
    int* cnt  = (int*)alloc((size_t)N_TOT*4);
    int* offA = (int*)alloc((size_t)N_TOT*4);
    int* btot = (int*)alloc(NBKT*4);
    int* bbase= (int*)alloc(NBKT*4);
    int* hist = (int*)alloc((size_t)NBKT*APAD*4);
    uint2* rec = (uint2*)alloc((size_t)E_TOT*8);     // {src, key}
    float* evb = (float*)alloc((size_t)E_TOT*4);
    int2* sorted2 = (int2*)alloc((size_t)E_TOT*8);   // {src, alpha}
    u16* knb   = (u16*)alloc((size_t)N_K*128*2);
    u16* exerb = (u16*)alloc((size_t)N_E*128*2);
    u16* stub  = (u16*)alloc((size_t)N_U*128*2);
    size_t need_bf = off_b;
    bool useBF = (ws_size >= need_bf);
    float* out = (float*)d_out;

    prep_w<<<360,256,0,stream>>>(W_und,W_ek,W_ke,W_eu,W_ue, a_und,a_ek,a_ke,a_eu,a_ue, vecs, Wf);

    if (useBF)
        conv_all<1><<<(170000+3)/4,256,0,stream>>>(kn, exer, stu, knb, exerb, stub, vecs,
                                                   el1, el2, el3, el4, el5, erc);
    else
        conv_all<0><<<(170000+3)/4,256,0,stream>>>(kn, exer, stu, knb, exerb, stub, vecs,
                                                   el1, el2, el3, el4, el5, erc);

    bkt_hist<<<NBLKA,256,0,stream>>>(und_dst, ek_src, ek_dst, eu_src, eu_dst, hist);
    bkt_scan1<<<NBKT,512,0,stream>>>(hist, btot);
    bkt_scan2<<<1,1024,0,stream>>>(btot, bbase);
    bkt_scatter<<<NBLKA,256,0,stream>>>(und_src, und_dst, ek_src, ek_dst, eu_src, eu_dst,
                                        hist, bbase, rec);
    bkt_finalize<<<NBKT,512,0,stream>>>(rec, bbase, btot, erc,
                                        el1, el2, el3, el4, el5, evb,
                                        cnt, offA, sorted2);

    if (useBF){
        agg_gemm_epi<1><<<KN_B+EX_B+ST_B,256,0,stream>>>(cnt, offA, sorted2,
            knb, exerb, stub, Wf,
            kfc2w,kfc2b,kfc3w,kfc3b, efc1w,efc1b,efc2w,efc2b, out);
    } else {
        agg_gemm_epi<0><<<KN_B+EX_B+ST_B,256,0,stream>>>(cnt, offA, sorted2,
            kn, exer, stu, Wf,
            kfc2w,kfc2b,kfc3w,kfc3b, efc1w,efc1b,efc2w,efc2b, out);
    }
}

// Round 14
// 273.369 us; speedup vs baseline: 1.1097x; 1.0640x over previous
//
#include <hip/hip_runtime.h>

#define N_K 20000
#define N_E 50000
#define N_U 100000
#define E_TOT 2200000
#define N_TOT 240000
// key-space (concat dst) bases
#define KB1 0
#define KB2 20000
#define KB3 40000
#define KB4 90000
#define KB5 190000
// bucket sort geometry
#define NBKT 726
#define EPB 8192
#define NBLKA 269          // ceil(E_TOT / EPB)
#define APAD 272
// fused agg+gemm block counts (16 nodes per block)
#define KN_B 1250
#define EX_B 3125
#define ST_B 6250

typedef unsigned short u16;
typedef unsigned int u32;
typedef __bf16 bf16x8 __attribute__((ext_vector_type(8)));
typedef float f32x4 __attribute__((ext_vector_type(4)));

__device__ __forceinline__ float bf2f(u16 v){
    union { u32 u; float f; } x; x.u = ((u32)v) << 16; return x.f;
}
__device__ __forceinline__ u16 f2bf(float f){
    union { float f; u32 u; } x; x.f = f;
    u32 r = x.u + 0x7FFFu + ((x.u >> 16) & 1u);
    return (u16)(r >> 16);
}
__device__ __forceinline__ float leaky_exp(float x){
    x = x >= 0.f ? x : 0.01f*x;
    return __expf(x);
}

// bucket mapping: per-range shifts, each bucket <=512 keys
__device__ __forceinline__ int bucket_of(int key){
    if (key < 20000)  return key >> 8;
    if (key < 40000)  return 79  + ((key - 20000) >> 7);
    if (key < 90000)  return 236 + ((key - 40000) >> 9);
    if (key < 190000) return 334 + ((key - 90000) >> 9);
    return 530 + ((key - 190000) >> 8);
}
__device__ __forceinline__ int local_of(int key){
    if (key < 20000)  return key & 255;
    if (key < 40000)  return (key - 20000) & 127;
    if (key < 90000)  return (key - 40000) & 511;
    if (key < 190000) return (key - 90000) & 511;
    return (key - 190000) & 255;
}
__device__ __forceinline__ void bucket_info(int b, int& kb, int& w, int& r){
    if (b < 79){       r=0; kb = b << 8;                 w = min(256, 20000  - kb); }
    else if (b < 236){ r=1; kb = 20000 + ((b-79)  << 7); w = min(128, 40000  - kb); }
    else if (b < 334){ r=2; kb = 40000 + ((b-236) << 9); w = min(512, 90000  - kb); }
    else if (b < 530){ r=3; kb = 90000 + ((b-334) << 9); w = min(512, 190000 - kb); }
    else {             r=4; kb = 190000 + ((b-530) << 8); w = min(256, 240000 - kb); }
}
__device__ __forceinline__ int edge_key(int e,
    const int* ud, const int* es, const int* ed, const int* vs, const int* vd){
    if (e < 200000)  return ud[e];
    if (e < 600000)  return 20000  + ed[e-200000];
    if (e < 1000000) return 40000  + es[e-600000];
    if (e < 1600000) return 90000  + vd[e-1000000];
    return 190000 + vs[e-1600000];
}
__device__ __forceinline__ int edge_src(int e,
    const int* us, const int* es, const int* ed, const int* vs, const int* vd){
    if (e < 200000)  return us[e];
    if (e < 600000)  return es[e-200000];
    if (e < 1000000) return ed[e-600000];
    if (e < 1600000) return vs[e-1000000];
    return vd[e-1600000];
}

// ------------------------------------------------- fused weight prep (vecs + MFMA frags)
__global__ __launch_bounds__(256) void prep_w(
    const float* W0, const float* W1, const float* W2, const float* W3, const float* W4,
    const float* a0, const float* a1, const float* a2, const float* a3, const float* a4,
    float* __restrict__ vecs, u16* __restrict__ Wf)
{
    int bid = blockIdx.x;
    if (bid < 320){
        int o = bid*4 + (threadIdx.x >> 6);
        int lane = threadIdx.x & 63;
        int which = o / 640, rem = o - which*640, g = rem >> 7, k = rem & 127;
        const float* W = g==0?W0:g==1?W1:g==2?W2:g==3?W3:W4;
        const float* a = g==0?a0:g==1?a1:g==2?a2:g==3?a3:a4;
        const float* av = a + which*128;
        int c = lane*2;
        float s = W[k*128 + c]*av[c] + W[k*128 + c + 1]*av[c+1];
        #pragma unroll
        for (int m = 32; m; m >>= 1) s += __shfl_xor(s, m);
        if (lane == 0) vecs[(which*5 + g)*128 + k] = s;
    } else {
        int t = (bid - 320)*256 + threadIdx.x;   // 0..10239
        int g = t / 2048, i = t - g*2048;
        const float* W = g==0?W0:g==1?W1:g==2?W2:g==3?W3:W4;
        int lane = i & 63, tt = i >> 6, ks = tt & 3, ct = tt >> 2;
        int kbase = ks*32 + (lane>>4)*8;
        int c = ct*16 + (lane&15);
        #pragma unroll
        for (int j = 0; j < 8; ++j)
            Wf[g*16384 + i*8 + j] = f2bf(W[(kbase+j)*128 + c]);
    }
}

// ------------------------------------------------- fused conv(f32->bf16) + row dots
template<int WBF>
__global__ __launch_bounds__(256) void conv_all(
    const float* __restrict__ kn, const float* __restrict__ exer, const float* __restrict__ stu,
    u16* __restrict__ knb, u16* __restrict__ exerb, u16* __restrict__ stub,
    const float* __restrict__ vecs,
    float* __restrict__ el1, float* __restrict__ el2, float* __restrict__ el3,
    float* __restrict__ el4, float* __restrict__ el5, float* __restrict__ erc)
{
    int w = (int)((blockIdx.x*(u32)blockDim.x + threadIdx.x) >> 6);
    int lane = threadIdx.x & 63;
    if (w >= 170000) return;
    const float* h; u16* hb; int local, nd;
    const float *v0,*v1,*v2,*v3;
    float *o0,*o1,*o2,*o3;
    if (w < 20000){
        local = w; h = kn; hb = knb; nd = 4;
        v0=vecs+0;    v1=vecs+640;  v2=vecs+768;  v3=vecs+256;
        o0=el1; o1=erc+KB1; o2=erc+KB2; o3=el3;
    } else if (w < 70000){
        local = w - 20000; h = exer; hb = exerb; nd = 4;
        v0=vecs+128;  v1=vecs+896;  v2=vecs+384;  v3=vecs+1152;
        o0=el2; o1=erc+KB3; o2=el4; o3=erc+KB5;
    } else {
        local = w - 70000; h = stu; hb = stub; nd = 2;
        v0=vecs+1024; v1=vecs+512;  v2=vecs;      v3=vecs;
        o0=erc+KB4; o1=el5; o2=nullptr; o3=nullptr;
    }
    float2 hv = *(const float2*)(h + (size_t)local*128 + lane*2);
    if (WBF)
        *(u32*)(hb + (size_t)local*128 + lane*2) = (u32)f2bf(hv.x) | ((u32)f2bf(hv.y) << 16);
    int c = lane*2;
    float d0 = hv.x*v0[c] + hv.y*v0[c+1];
    float d1 = hv.x*v1[c] + hv.y*v1[c+1];
    float d2 = hv.x*v2[c] + hv.y*v2[c+1];
    float d3 = hv.x*v3[c] + hv.y*v3[c+1];
    #pragma unroll
    for (int o = 32; o; o >>= 1){
        d0 += __shfl_xor(d0, o); d1 += __shfl_xor(d1, o);
        d2 += __shfl_xor(d2, o); d3 += __shfl_xor(d3, o);
    }
    if (lane == 0){
        o0[local] = d0; o1[local] = d1;
        if (nd == 4){ o2[local] = d2; o3[local] = d3; }
    }
}

// ------------------------------------------------- atomic-free CSR build
__global__ __launch_bounds__(256) void bkt_hist(
    const int* __restrict__ ud, const int* __restrict__ es, const int* __restrict__ ed,
    const int* __restrict__ vs, const int* __restrict__ vd, int* __restrict__ hist)
{
    __shared__ int h[NBKT];
    for (int i = threadIdx.x; i < NBKT; i += 256) h[i] = 0;
    __syncthreads();
    int base = blockIdx.x * EPB;
    #pragma unroll 4
    for (int it = 0; it < EPB/256; ++it){
        int e = base + it*256 + threadIdx.x;
        if (e < E_TOT){
            int key = edge_key(e, ud, es, ed, vs, vd);
            atomicAdd(&h[bucket_of(key)], 1);
        }
    }
    __syncthreads();
    for (int i = threadIdx.x; i < NBKT; i += 256)
        hist[i*APAD + blockIdx.x] = h[i];
}

__global__ __launch_bounds__(512) void bkt_scan1(int* __restrict__ hist, int* __restrict__ btot)
{
    __shared__ int sm[512];
    int t = threadIdx.x;
    int v = (t < NBLKA) ? hist[blockIdx.x*APAD + t] : 0;
    sm[t] = v; __syncthreads();
    #pragma unroll
    for (int d = 1; d < 512; d <<= 1){
        int x = (t >= d) ? sm[t-d] : 0;
        __syncthreads();
        sm[t] += x;
        __syncthreads();
    }
    if (t < NBLKA) hist[blockIdx.x*APAD + t] = sm[t] - v;
    if (t == 511) btot[blockIdx.x] = sm[511];
}

__global__ __launch_bounds__(1024) void bkt_scan2(const int* __restrict__ btot, int* __restrict__ bbase)
{
    __shared__ int sm[1024];
    int t = threadIdx.x;
    int v = (t < NBKT) ? btot[t] : 0;
    sm[t] = v; __syncthreads();
    #pragma unroll
    for (int d = 1; d < 1024; d <<= 1){
        int x = (t >= d) ? sm[t-d] : 0;
        __syncthreads();
        sm[t] += x;
        __syncthreads();
    }
    if (t < NBKT) bbase[t] = sm[t] - v;
}

// scatter packed records {src | local<<17} (u32 — halves record traffic);
// LDS cursors only. No ev compute here (r12 lesson: 4 waves/CU can't hide it).
__global__ __launch_bounds__(256) void bkt_scatter(
    const int* __restrict__ us, const int* __restrict__ ud,
    const int* __restrict__ es, const int* __restrict__ ed,
    const int* __restrict__ vs, const int* __restrict__ vd,
    const int* __restrict__ hist, const int* __restrict__ bbase,
    u32* __restrict__ rec)
{
    __shared__ int cur[NBKT];
    for (int i = threadIdx.x; i < NBKT; i += 256)
        cur[i] = bbase[i] + hist[i*APAD + blockIdx.x];
    __syncthreads();
    int base = blockIdx.x * EPB;
    #pragma unroll 4
    for (int it = 0; it < EPB/256; ++it){
        int e = base + it*256 + threadIdx.x;
        if (e < E_TOT){
            int key = edge_key(e, ud, es, ed, vs, vd);
            int src = edge_src(e, us, es, ed, vs, vd);
            int local = local_of(key);
            int pos = atomicAdd(&cur[bucket_of(key)], 1);
            rec[pos] = (u32)src | ((u32)local << 17);
        }
    }
}

// per-bucket: key hist + ev-sum -> cnt/offA (bbase + LDS scan), then place
// {src, alpha=ev/sum}. ev computed here (726x512 threads hide gather latency);
// cached in evb so pass 2 skips the el re-gather + exp.
__global__ __launch_bounds__(512) void bkt_finalize(const u32* __restrict__ rec,
    const int* __restrict__ bbase, const int* __restrict__ btot,
    const float* __restrict__ erc,
    const float* __restrict__ el1, const float* __restrict__ el2,
    const float* __restrict__ el3, const float* __restrict__ el4,
    const float* __restrict__ el5, float* __restrict__ evb,
    int* __restrict__ cnt, int* __restrict__ offA, int2* __restrict__ sorted2)
{
    __shared__ int   h[512];
    __shared__ float s[512];
    __shared__ float ercs[512];
    __shared__ int   sm[512];
    __shared__ int   curk[512];
    int b = blockIdx.x, t = threadIdx.x;
    int kb, w, r;
    bucket_info(b, kb, w, r);
    h[t] = 0; s[t] = 0.f;
    if (t < w) ercs[t] = erc[kb + t];
    __syncthreads();
    const float* el = r==0?el1 : r==1?el2 : r==2?el3 : r==3?el4 : el5;
    int start = bbase[b], n = btot[b];
    for (int i = t; i < n; i += 512){
        u32 rc = rec[start + i];
        int local = (int)(rc >> 17);
        float ev = leaky_exp(el[rc & 0x1FFFFu] + ercs[local]);
        evb[start + i] = ev;
        atomicAdd(&h[local], 1);
        atomicAdd(&s[local], ev);
    }
    __syncthreads();
    int hv = h[t];
    if (t < w) cnt[kb + t] = hv;
    sm[t] = hv; __syncthreads();
    #pragma unroll
    for (int d = 1; d < 512; d <<= 1){
        int x = (t >= d) ? sm[t-d] : 0;
        __syncthreads();
        sm[t] += x;
        __syncthreads();
    }
    int pos0 = start + sm[t] - hv;
    if (t < w) offA[kb + t] = pos0;
    curk[t] = pos0;
    __syncthreads();
    for (int i = t; i < n; i += 512){
        u32 rc = rec[start + i];
        int local = (int)(rc >> 17);
        float alpha = evb[start + i] / s[local];
        int pos = atomicAdd(&curk[local], 1);
        sorted2[pos] = make_int2((int)(rc & 0x1FFFFu), __float_as_int(alpha));
    }
}

// ------------------------------------------------- fused aggregation + dual-GEMM + epilogue
// Wide-gather layout (r12 config — best found): 16 lanes per edge-row
// (16B/lane), 4 edges per wave-instruction, single-depth paired streams.
// (r13's 2-deep pipeline REGRESSED: VGPR 48->56 cost occupancy 53->42%.)
template<int BF>
__global__ __launch_bounds__(256) void agg_gemm_epi(
    const int* __restrict__ cnt, const int* __restrict__ offA, const int2* __restrict__ sorted2,
    const void* __restrict__ hk, const void* __restrict__ he, const void* __restrict__ hs,
    const u16* __restrict__ Wf,
    const float* __restrict__ kfc2w, const float* __restrict__ kfc2b,
    const float* __restrict__ kfc3w, const float* __restrict__ kfc3b,
    const float* __restrict__ efc1w, const float* __restrict__ efc1b,
    const float* __restrict__ efc2w, const float* __restrict__ efc2b,
    float* __restrict__ out)
{
    __shared__ u16 ldsC[16*136];
    __shared__ u16 ldsD[16*136];
    __shared__ float sred2[16], sred3[16], p2s[16], p3s[16];

    int bid = blockIdx.x;
    int wave = threadIdx.x >> 6, lane = threadIdx.x & 63;
    int g = lane >> 4, s = lane & 15;
    int kind, node0, keyC, keyD;
    const void *hC, *hD, *Aseg;
    const u16 *wc, *wd;
    const float *w2, *b2, *w3, *b3;
    float* outp;
    if (bid < KN_B){
        kind=0; node0 = bid*16;
        keyC = KB1 + node0; keyD = KB2 + node0;
        hC = hk; hD = he; Aseg = hk;
        wc = Wf; wd = Wf + 16384;
        w2=kfc2w; b2=kfc2b; w3=kfc3w; b3=kfc3b;
        outp = out;
    } else if (bid < KN_B + EX_B){
        kind=0; node0 = (bid - KN_B)*16;
        keyC = KB3 + node0; keyD = KB5 + node0;
        hC = hk; hD = hs; Aseg = he;
        wc = Wf + 2*16384; wd = Wf + 4*16384;
        w2=efc1w; b2=efc1b; w3=efc2w; b3=efc2b;
        outp = out + (size_t)N_K*128;
    } else {
        kind=1; node0 = (bid - KN_B - EX_B)*16;
        keyC = KB4 + node0; keyD = 0;
        hC = he; hD = nullptr; Aseg = hs;
        wc = Wf + 3*16384; wd = nullptr;
        w2=nullptr; b2=nullptr; w3=nullptr; b3=nullptr;
        outp = out + (size_t)(N_K + N_E)*128;
    }

    // ---- aggregation into LDS: paired rows, 4-edge-wide chunks ----
    int rpw = (kind == 0) ? 8 : 4;
    for (int rr = 0; rr < rpw; rr += 2){
        int cA = wave*rpw + rr;                 // even -> pair stays in one seg
        int seg = cA >> 4, ndA = cA & 15;
        int keyA = (seg == 0 ? keyC : keyD) + ndA;
        const u16* hb = (const u16*)(seg == 0 ? hC : hD);
        const float4* hf = (const float4*)(seg == 0 ? hC : hD);
        int degA = cnt[keyA],     startA = offA[keyA];
        int degB = cnt[keyA + 1], startB = offA[keyA + 1];
        float aA8[8], aB8[8];
        #pragma unroll
        for (int k = 0; k < 8; ++k){ aA8[k] = 0.f; aB8[k] = 0.f; }

        auto chunk = [&](const int2* sp, float* acc){
            int2 w = sp[g];
            float al = __int_as_float(w.y);
            if (BF){
                uint4 hv = *(const uint4*)(hb + (size_t)w.x*128 + s*8);
                acc[0] = fmaf(al, bf2f((u16)hv.x), acc[0]);
                acc[1] = fmaf(al, bf2f((u16)(hv.x>>16)), acc[1]);
                acc[2] = fmaf(al, bf2f((u16)hv.y), acc[2]);
                acc[3] = fmaf(al, bf2f((u16)(hv.y>>16)), acc[3]);
                acc[4] = fmaf(al, bf2f((u16)hv.z), acc[4]);
                acc[5] = fmaf(al, bf2f((u16)(hv.z>>16)), acc[5]);
                acc[6] = fmaf(al, bf2f((u16)hv.w), acc[6]);
                acc[7] = fmaf(al, bf2f((u16)(hv.w>>16)), acc[7]);
            } else {
                const float4* rp = hf + (size_t)w.x*32 + s*2;
                float4 p0 = rp[0], p1 = rp[1];
                acc[0] = fmaf(al, p0.x, acc[0]); acc[1] = fmaf(al, p0.y, acc[1]);
                acc[2] = fmaf(al, p0.z, acc[2]); acc[3] = fmaf(al, p0.w, acc[3]);
                acc[4] = fmaf(al, p1.x, acc[4]); acc[5] = fmaf(al, p1.y, acc[5]);
                acc[6] = fmaf(al, p1.z, acc[6]); acc[7] = fmaf(al, p1.w, acc[7]);
            }
        };

        int iA = 0, iB = 0;
        while (iA + 4 <= degA && iB + 4 <= degB){
            chunk(sorted2 + startA + iA, aA8);
            chunk(sorted2 + startB + iB, aB8);
            iA += 4; iB += 4;
        }
        for (; iA + 4 <= degA; iA += 4) chunk(sorted2 + startA + iA, aA8);
        for (; iB + 4 <= degB; iB += 4) chunk(sorted2 + startB + iB, aB8);
        int remA = degA - iA;
        if (g < remA) chunk(sorted2 + startA + iA, aA8);   // per-group predicated tail
        int remB = degB - iB;
        if (g < remB) chunk(sorted2 + startB + iB, aB8);

        // merge the 4 lane-groups (same columns, disjoint edge subsets)
        #pragma unroll
        for (int k = 0; k < 8; ++k){
            aA8[k] += __shfl_xor(aA8[k], 16); aA8[k] += __shfl_xor(aA8[k], 32);
            aB8[k] += __shfl_xor(aB8[k], 16); aB8[k] += __shfl_xor(aB8[k], 32);
        }
        u16* ldsSeg = (seg == 0 ? ldsC : ldsD);
        if (lane < 16){
            u32 p0 = (u32)f2bf(aA8[0]) | ((u32)f2bf(aA8[1]) << 16);
            u32 p1 = (u32)f2bf(aA8[2]) | ((u32)f2bf(aA8[3]) << 16);
            u32 p2 = (u32)f2bf(aA8[4]) | ((u32)f2bf(aA8[5]) << 16);
            u32 p3 = (u32)f2bf(aA8[6]) | ((u32)f2bf(aA8[7]) << 16);
            *(uint4*)(ldsSeg + ndA*136 + lane*8) = make_uint4(p0,p1,p2,p3);
            u32 q0 = (u32)f2bf(aB8[0]) | ((u32)f2bf(aB8[1]) << 16);
            u32 q1 = (u32)f2bf(aB8[2]) | ((u32)f2bf(aB8[3]) << 16);
            u32 q2 = (u32)f2bf(aB8[4]) | ((u32)f2bf(aB8[5]) << 16);
            u32 q3 = (u32)f2bf(aB8[6]) | ((u32)f2bf(aB8[7]) << 16);
            *(uint4*)(ldsSeg + (ndA+1)*136 + lane*8) = make_uint4(q0,q1,q2,q3);
        }
    }
    if (threadIdx.x < 16){ sred2[threadIdx.x] = 0.f; sred3[threadIdx.x] = 0.f; }
    __syncthreads();

    // ---- GEMM phase: wave handles ct = 2*wave, 2*wave+1 ----
    int colb = lane & 15, rlo = (lane >> 4)*4;
    const float* Af = (const float*)Aseg;
    const u16*   Ab = (const u16*)Aseg;

    bf16x8 afC[4];
    #pragma unroll
    for (int ks = 0; ks < 4; ++ks)
        afC[ks] = *(const bf16x8*)(ldsC + (lane & 15)*136 + ks*32 + (lane >> 4)*8);
    f32x4 accC[2];
    accC[0] = (f32x4){0.f,0.f,0.f,0.f}; accC[1] = (f32x4){0.f,0.f,0.f,0.f};
    #pragma unroll
    for (int ci = 0; ci < 2; ++ci){
        int ct = wave*2 + ci;
        #pragma unroll
        for (int ks = 0; ks < 4; ++ks){
            bf16x8 bfr = *(const bf16x8*)(wc + ((ct*4+ks)*64 + lane)*8);
            accC[ci] = __builtin_amdgcn_mfma_f32_16x16x32_bf16(afC[ks], bfr, accC[ci], 0, 0, 0);
        }
    }

    if (kind == 1){
        #pragma unroll
        for (int ci = 0; ci < 2; ++ci){
            int ct = wave*2 + ci;
            #pragma unroll
            for (int j = 0; j < 4; ++j){
                size_t idx = (size_t)(node0 + rlo + j)*128 + ct*16 + colb;
                float av = BF ? bf2f(Ab[idx]) : Af[idx];
                outp[idx] = accC[ci][j] + av;
            }
        }
        return;
    }

    bf16x8 afD[4];
    #pragma unroll
    for (int ks = 0; ks < 4; ++ks)
        afD[ks] = *(const bf16x8*)(ldsD + (lane & 15)*136 + ks*32 + (lane >> 4)*8);
    f32x4 accD[2];
    accD[0] = (f32x4){0.f,0.f,0.f,0.f}; accD[1] = (f32x4){0.f,0.f,0.f,0.f};
    #pragma unroll
    for (int ci = 0; ci < 2; ++ci){
        int ct = wave*2 + ci;
        #pragma unroll
        for (int ks = 0; ks < 4; ++ks){
            bf16x8 bfr = *(const bf16x8*)(wd + ((ct*4+ks)*64 + lane)*8);
            accD[ci] = __builtin_amdgcn_mfma_f32_16x16x32_bf16(afD[ks], bfr, accD[ci], 0, 0, 0);
        }
    }

    float aA[2][4];
    float s2p[4] = {0.f,0.f,0.f,0.f}, s3p[4] = {0.f,0.f,0.f,0.f};
    #pragma unroll
    for (int ci = 0; ci < 2; ++ci){
        int ct = wave*2 + ci;
        float w2l = w2[ct*16 + colb], w2h = w2[128 + ct*16 + colb];
        float w3l = w3[ct*16 + colb], w3h = w3[128 + ct*16 + colb];
        #pragma unroll
        for (int j = 0; j < 4; ++j){
            size_t idx = (size_t)(node0 + rlo + j)*128 + ct*16 + colb;
            float av = BF ? bf2f(Ab[idx]) : Af[idx];
            aA[ci][j] = av;
            s2p[j] = fmaf(av, w2l, fmaf(accC[ci][j], w2h, s2p[j]));
            s3p[j] = fmaf(av, w3l, fmaf(accD[ci][j], w3h, s3p[j]));
        }
    }
    #pragma unroll
    for (int m = 8; m; m >>= 1)
        #pragma unroll
        for (int j = 0; j < 4; ++j){
            s2p[j] += __shfl_xor(s2p[j], m);
            s3p[j] += __shfl_xor(s3p[j], m);
        }
    if (colb == 0){
        #pragma unroll
        for (int j = 0; j < 4; ++j){
            atomicAdd(&sred2[rlo + j], s2p[j]);
            atomicAdd(&sred3[rlo + j], s3p[j]);
        }
    }
    __syncthreads();
    if (threadIdx.x < 16){
        float s2 = sred2[threadIdx.x] + b2[0];
        float s3 = sred3[threadIdx.x] + b3[0];
        float mx = fmaxf(s2, s3);
        float e2 = __expf(s2 - mx), e3 = __expf(s3 - mx);
        float inv = 1.f/(e2 + e3);
        p2s[threadIdx.x] = e2*inv;
        p3s[threadIdx.x] = e3*inv;
    }
    __syncthreads();
    #pragma unroll
    for (int ci = 0; ci < 2; ++ci){
        int ct = wave*2 + ci;
        #pragma unroll
        for (int j = 0; j < 4; ++j){
            int row = rlo + j;
            size_t idx = (size_t)(node0 + row)*128 + ct*16 + colb;
            outp[idx] = aA[ci][j] + p2s[row]*accC[ci][j] + p3s[row]*accD[ci][j];
        }
    }
}

extern "C" void kernel_launch(void* const* d_in, const int* in_sizes, int n_in,
                              void* d_out, int out_size, void* d_ws, size_t ws_size,
                              hipStream_t stream)
{
    (void)in_sizes; (void)n_in; (void)out_size;
    const float* kn   = (const float*)d_in[0];
    const float* exer = (const float*)d_in[1];
    const float* stu  = (const float*)d_in[2];
    const int* und_src = (const int*)d_in[3];
    const int* und_dst = (const int*)d_in[4];
    const int* ek_src  = (const int*)d_in[5];
    const int* ek_dst  = (const int*)d_in[6];
    const int* eu_src  = (const int*)d_in[7];
    const int* eu_dst  = (const int*)d_in[8];
    const float* W_und = (const float*)d_in[9];  const float* a_und = (const float*)d_in[10];
    const float* W_ek  = (const float*)d_in[11]; const float* a_ek  = (const float*)d_in[12];
    const float* W_ke  = (const float*)d_in[13]; const float* a_ke  = (const float*)d_in[14];
    const float* W_eu  = (const float*)d_in[15]; const float* a_eu  = (const float*)d_in[16];
    const float* W_ue  = (const float*)d_in[17]; const float* a_ue  = (const float*)d_in[18];
    const float* kfc2w = (const float*)d_in[19]; const float* kfc2b = (const float*)d_in[20];
    const float* kfc3w = (const float*)d_in[21]; const float* kfc3b = (const float*)d_in[22];
    const float* efc1w = (const float*)d_in[23]; const float* efc1b = (const float*)d_in[24];
    const float* efc2w = (const float*)d_in[25]; const float* efc2b = (const float*)d_in[26];

    char* base = (char*)d_ws;
    size_t off_b = 0;
    auto alloc = [&](size_t bytes)->char*{
        char* p = base + off_b;
        off_b += (bytes + 255) & ~(size_t)255;
        return p;
    };
    float* vecs = (float*)alloc(1280*4);
    u16*   Wf   = (u16*)  alloc(5*16384*2);
    float* el1 = (float*)alloc(N_K*4);
    float* el2 = (float*)alloc(N_E*4);
    float* el3 = (float*)alloc(N_K*4);
    float* el4 = (float*)alloc(N_E*4);
    float* el5 = (float*)alloc(N_U*4);
    float* erc = (float*)alloc((size_t)N_TOT*4);
    int* cnt  = (int*)alloc((size_t)N_TOT*4);
    int* offA = (int*)alloc((size_t)N_TOT*4);
    int* btot = (int*)alloc(NBKT*4);
    int* bbase= (int*)alloc(NBKT*4);
    int* hist = (int*)alloc((size_t)NBKT*APAD*4);
    u32* rec  = (u32*)alloc((size_t)E_TOT*4);        // {src | local<<17} packed
    float* evb = (float*)alloc((size_t)E_TOT*4);
    int2* sorted2 = (int2*)alloc((size_t)E_TOT*8);   // {src, alpha}
    u16* knb   = (u16*)alloc((size_t)N_K*128*2);
    u16* exerb = (u16*)alloc((size_t)N_E*128*2);
    u16* stub  = (u16*)alloc((size_t)N_U*128*2);
    size_t need_bf = off_b;
    bool useBF = (ws_size >= need_bf);
    float* out = (float*)d_out;

    prep_w<<<360,256,0,stream>>>(W_und,W_ek,W_ke,W_eu,W_ue, a_und,a_ek,a_ke,a_eu,a_ue, vecs, Wf);

    if (useBF)
        conv_all<1><<<(170000+3)/4,256,0,stream>>>(kn, exer, stu, knb, exerb, stub, vecs,
                                                   el1, el2, el3, el4, el5, erc);
    else
        conv_all<0><<<(170000+3)/4,256,0,stream>>>(kn, exer, stu, knb, exerb, stub, vecs,
                                                   el1, el2, el3, el4, el5, erc);

    bkt_hist<<<NBLKA,256,0,stream>>>(und_dst, ek_src, ek_dst, eu_src, eu_dst, hist);
    bkt_scan1<<<NBKT,512,0,stream>>>(hist, btot);
    bkt_scan2<<<1,1024,0,stream>>>(btot, bbase);
    bkt_scatter<<<NBLKA,256,0,stream>>>(und_src, und_dst, ek_src, ek_dst, eu_src, eu_dst,
                                        hist, bbase, rec);
    bkt_finalize<<<NBKT,512,0,stream>>>(rec, bbase, btot, erc,
                                        el1, el2, el3, el4, el5, evb,
                                        cnt, offA, sorted2);

    if (useBF){
        agg_gemm_epi<1><<<KN_B+EX_B+ST_B,256,0,stream>>>(cnt, offA, sorted2,
            knb, exerb, stub, Wf,
            kfc2w,kfc2b,kfc3w,kfc3b, efc1w,efc1b,efc2w,efc2b, out);
    } else {
        agg_gemm_epi<0><<<KN_B+EX_B+ST_B,256,0,stream>>>(cnt, offA, sorted2,
            kn, exer, stu, Wf,
            kfc2w,kfc2b,kfc3w,kfc3b, efc1w,efc1b,efc2w,efc2b, out);
    }
}

// Round 15
// 256.412 us; speedup vs baseline: 1.1831x; 1.0661x over previous
//
#include <hip/hip_runtime.h>

#define N_K 20000
#define N_E 50000
#define N_U 100000
#define E_TOT 2200000
#define N_TOT 240000
// key-space (concat dst) bases
#define KB1 0
#define KB2 20000
#define KB3 40000
#define KB4 90000
#define KB5 190000
// bucket sort geometry (r15: EPB 8192->2048 so hist/scatter get ~17 waves/CU)
#define NBKT 726
#define EPB 2048
#define NBLKA 1075         // ceil(E_TOT / EPB)
#define APAD 1088
// fused agg+gemm block counts (16 nodes per block)
#define KN_B 1250
#define EX_B 3125
#define ST_B 6250

typedef unsigned short u16;
typedef unsigned int u32;
typedef __bf16 bf16x8 __attribute__((ext_vector_type(8)));
typedef float f32x4 __attribute__((ext_vector_type(4)));

__device__ __forceinline__ float bf2f(u16 v){
    union { u32 u; float f; } x; x.u = ((u32)v) << 16; return x.f;
}
__device__ __forceinline__ u16 f2bf(float f){
    union { float f; u32 u; } x; x.f = f;
    u32 r = x.u + 0x7FFFu + ((x.u >> 16) & 1u);
    return (u16)(r >> 16);
}
__device__ __forceinline__ float leaky_exp(float x){
    x = x >= 0.f ? x : 0.01f*x;
    return __expf(x);
}

// bucket mapping: per-range shifts, each bucket <=512 keys
__device__ __forceinline__ int bucket_of(int key){
    if (key < 20000)  return key >> 8;
    if (key < 40000)  return 79  + ((key - 20000) >> 7);
    if (key < 90000)  return 236 + ((key - 40000) >> 9);
    if (key < 190000) return 334 + ((key - 90000) >> 9);
    return 530 + ((key - 190000) >> 8);
}
__device__ __forceinline__ int local_of(int key){
    if (key < 20000)  return key & 255;
    if (key < 40000)  return (key - 20000) & 127;
    if (key < 90000)  return (key - 40000) & 511;
    if (key < 190000) return (key - 90000) & 511;
    return (key - 190000) & 255;
}
__device__ __forceinline__ void bucket_info(int b, int& kb, int& w, int& r){
    if (b < 79){       r=0; kb = b << 8;                 w = min(256, 20000  - kb); }
    else if (b < 236){ r=1; kb = 20000 + ((b-79)  << 7); w = min(128, 40000  - kb); }
    else if (b < 334){ r=2; kb = 40000 + ((b-236) << 9); w = min(512, 90000  - kb); }
    else if (b < 530){ r=3; kb = 90000 + ((b-334) << 9); w = min(512, 190000 - kb); }
    else {             r=4; kb = 190000 + ((b-530) << 8); w = min(256, 240000 - kb); }
}
__device__ __forceinline__ int edge_key(int e,
    const int* ud, const int* es, const int* ed, const int* vs, const int* vd){
    if (e < 200000)  return ud[e];
    if (e < 600000)  return 20000  + ed[e-200000];
    if (e < 1000000) return 40000  + es[e-600000];
    if (e < 1600000) return 90000  + vd[e-1000000];
    return 190000 + vs[e-1600000];
}
__device__ __forceinline__ int edge_src(int e,
    const int* us, const int* es, const int* ed, const int* vs, const int* vd){
    if (e < 200000)  return us[e];
    if (e < 600000)  return es[e-200000];
    if (e < 1000000) return ed[e-600000];
    if (e < 1600000) return vs[e-1000000];
    return vd[e-1600000];
}

// ------------------------------------------------- fused weight prep (vecs + MFMA frags)
__global__ __launch_bounds__(256) void prep_w(
    const float* W0, const float* W1, const float* W2, const float* W3, const float* W4,
    const float* a0, const float* a1, const float* a2, const float* a3, const float* a4,
    float* __restrict__ vecs, u16* __restrict__ Wf)
{
    int bid = blockIdx.x;
    if (bid < 320){
        int o = bid*4 + (threadIdx.x >> 6);
        int lane = threadIdx.x & 63;
        int which = o / 640, rem = o - which*640, g = rem >> 7, k = rem & 127;
        const float* W = g==0?W0:g==1?W1:g==2?W2:g==3?W3:W4;
        const float* a = g==0?a0:g==1?a1:g==2?a2:g==3?a3:a4;
        const float* av = a + which*128;
        int c = lane*2;
        float s = W[k*128 + c]*av[c] + W[k*128 + c + 1]*av[c+1];
        #pragma unroll
        for (int m = 32; m; m >>= 1) s += __shfl_xor(s, m);
        if (lane == 0) vecs[(which*5 + g)*128 + k] = s;
    } else {
        int t = (bid - 320)*256 + threadIdx.x;   // 0..10239
        int g = t / 2048, i = t - g*2048;
        const float* W = g==0?W0:g==1?W1:g==2?W2:g==3?W3:W4;
        int lane = i & 63, tt = i >> 6, ks = tt & 3, ct = tt >> 2;
        int kbase = ks*32 + (lane>>4)*8;
        int c = ct*16 + (lane&15);
        #pragma unroll
        for (int j = 0; j < 8; ++j)
            Wf[g*16384 + i*8 + j] = f2bf(W[(kbase+j)*128 + c]);
    }
}

// ------------------------------------------------- fused conv(f32->bf16) + row dots
template<int WBF>
__global__ __launch_bounds__(256) void conv_all(
    const float* __restrict__ kn, const float* __restrict__ exer, const float* __restrict__ stu,
    u16* __restrict__ knb, u16* __restrict__ exerb, u16* __restrict__ stub,
    const float* __restrict__ vecs,
    float* __restrict__ el1, float* __restrict__ el2, float* __restrict__ el3,
    float* __restrict__ el4, float* __restrict__ el5, float* __restrict__ erc)
{
    int w = (int)((blockIdx.x*(u32)blockDim.x + threadIdx.x) >> 6);
    int lane = threadIdx.x & 63;
    if (w >= 170000) return;
    const float* h; u16* hb; int local, nd;
    const float *v0,*v1,*v2,*v3;
    float *o0,*o1,*o2,*o3;
    if (w < 20000){
        local = w; h = kn; hb = knb; nd = 4;
        v0=vecs+0;    v1=vecs+640;  v2=vecs+768;  v3=vecs+256;
        o0=el1; o1=erc+KB1; o2=erc+KB2; o3=el3;
    } else if (w < 70000){
        local = w - 20000; h = exer; hb = exerb; nd = 4;
        v0=vecs+128;  v1=vecs+896;  v2=vecs+384;  v3=vecs+1152;
        o0=el2; o1=erc+KB3; o2=el4; o3=erc+KB5;
    } else {
        local = w - 70000; h = stu; hb = stub; nd = 2;
        v0=vecs+1024; v1=vecs+512;  v2=vecs;      v3=vecs;
        o0=erc+KB4; o1=el5; o2=nullptr; o3=nullptr;
    }
    float2 hv = *(const float2*)(h + (size_t)local*128 + lane*2);
    if (WBF)
        *(u32*)(hb + (size_t)local*128 + lane*2) = (u32)f2bf(hv.x) | ((u32)f2bf(hv.y) << 16);
    int c = lane*2;
    float d0 = hv.x*v0[c] + hv.y*v0[c+1];
    float d1 = hv.x*v1[c] + hv.y*v1[c+1];
    float d2 = hv.x*v2[c] + hv.y*v2[c+1];
    float d3 = hv.x*v3[c] + hv.y*v3[c+1];
    #pragma unroll
    for (int o = 32; o; o >>= 1){
        d0 += __shfl_xor(d0, o); d1 += __shfl_xor(d1, o);
        d2 += __shfl_xor(d2, o); d3 += __shfl_xor(d3, o);
    }
    if (lane == 0){
        o0[local] = d0; o1[local] = d1;
        if (nd == 4){ o2[local] = d2; o3[local] = d3; }
    }
}

// ------------------------------------------------- atomic-free CSR build
__global__ __launch_bounds__(256) void bkt_hist(
    const int* __restrict__ ud, const int* __restrict__ es, const int* __restrict__ ed,
    const int* __restrict__ vs, const int* __restrict__ vd, int* __restrict__ hist)
{
    __shared__ int h[NBKT];
    for (int i = threadIdx.x; i < NBKT; i += 256) h[i] = 0;
    __syncthreads();
    int base = blockIdx.x * EPB;
    #pragma unroll 4
    for (int it = 0; it < EPB/256; ++it){
        int e = base + it*256 + threadIdx.x;
        if (e < E_TOT){
            int key = edge_key(e, ud, es, ed, vs, vd);
            atomicAdd(&h[bucket_of(key)], 1);
        }
    }
    __syncthreads();
    for (int i = threadIdx.x; i < NBKT; i += 256)
        hist[i*APAD + blockIdx.x] = h[i];
}

// per bucket: exclusive scan over NBLKA block entries, 3 sequential 512-chunks
__global__ __launch_bounds__(512) void bkt_scan1(int* __restrict__ hist, int* __restrict__ btot)
{
    __shared__ int sm[512];
    int t = threadIdx.x;
    int off = 0;
    #pragma unroll
    for (int c = 0; c < 3; ++c){
        int i = c*512 + t;
        int v = (i < NBLKA) ? hist[blockIdx.x*APAD + i] : 0;
        sm[t] = v; __syncthreads();
        #pragma unroll
        for (int d = 1; d < 512; d <<= 1){
            int x = (t >= d) ? sm[t-d] : 0;
            __syncthreads();
            sm[t] += x;
            __syncthreads();
        }
        if (i < NBLKA) hist[blockIdx.x*APAD + i] = off + sm[t] - v;
        off += sm[511];
        __syncthreads();
    }
    if (t == 0) btot[blockIdx.x] = off;
}

__global__ __launch_bounds__(1024) void bkt_scan2(const int* __restrict__ btot, int* __restrict__ bbase)
{
    __shared__ int sm[1024];
    int t = threadIdx.x;
    int v = (t < NBKT) ? btot[t] : 0;
    sm[t] = v; __syncthreads();
    #pragma unroll
    for (int d = 1; d < 1024; d <<= 1){
        int x = (t >= d) ? sm[t-d] : 0;
        __syncthreads();
        sm[t] += x;
        __syncthreads();
    }
    if (t < NBKT) bbase[t] = sm[t] - v;
}

// scatter packed records {src | local<<17} (u32); LDS cursors only.
__global__ __launch_bounds__(256) void bkt_scatter(
    const int* __restrict__ us, const int* __restrict__ ud,
    const int* __restrict__ es, const int* __restrict__ ed,
    const int* __restrict__ vs, const int* __restrict__ vd,
    const int* __restrict__ hist, const int* __restrict__ bbase,
    u32* __restrict__ rec)
{
    __shared__ int cur[NBKT];
    for (int i = threadIdx.x; i < NBKT; i += 256)
        cur[i] = bbase[i] + hist[i*APAD + blockIdx.x];
    __syncthreads();
    int base = blockIdx.x * EPB;
    #pragma unroll 4
    for (int it = 0; it < EPB/256; ++it){
        int e = base + it*256 + threadIdx.x;
        if (e < E_TOT){
            int key = edge_key(e, ud, es, ed, vs, vd);
            int src = edge_src(e, us, es, ed, vs, vd);
            int local = local_of(key);
            int pos = atomicAdd(&cur[bucket_of(key)], 1);
            rec[pos] = (u32)src | ((u32)local << 17);
        }
    }
}

// per-bucket: key hist + ev-sum -> cnt/offA (bbase + LDS scan), then place
// {src, alpha=ev/sum}. ev computed here (726x512 threads hide gather latency);
// cached in evb so pass 2 skips the el re-gather + exp.
__global__ __launch_bounds__(512) void bkt_finalize(const u32* __restrict__ rec,
    const int* __restrict__ bbase, const int* __restrict__ btot,
    const float* __restrict__ erc,
    const float* __restrict__ el1, const float* __restrict__ el2,
    const float* __restrict__ el3, const float* __restrict__ el4,
    const float* __restrict__ el5, float* __restrict__ evb,
    int* __restrict__ cnt, int* __restrict__ offA, int2* __restrict__ sorted2)
{
    __shared__ int   h[512];
    __shared__ float s[512];
    __shared__ float ercs[512];
    __shared__ int   sm[512];
    __shared__ int   curk[512];
    int b = blockIdx.x, t = threadIdx.x;
    int kb, w, r;
    bucket_info(b, kb, w, r);
    h[t] = 0; s[t] = 0.f;
    if (t < w) ercs[t] = erc[kb + t];
    __syncthreads();
    const float* el = r==0?el1 : r==1?el2 : r==2?el3 : r==3?el4 : el5;
    int start = bbase[b], n = btot[b];
    for (int i = t; i < n; i += 512){
        u32 rc = rec[start + i];
        int local = (int)(rc >> 17);
        float ev = leaky_exp(el[rc & 0x1FFFFu] + ercs[local]);
        evb[start + i] = ev;
        atomicAdd(&h[local], 1);
        atomicAdd(&s[local], ev);
    }
    __syncthreads();
    int hv = h[t];
    if (t < w) cnt[kb + t] = hv;
    sm[t] = hv; __syncthreads();
    #pragma unroll
    for (int d = 1; d < 512; d <<= 1){
        int x = (t >= d) ? sm[t-d] : 0;
        __syncthreads();
        sm[t] += x;
        __syncthreads();
    }
    int pos0 = start + sm[t] - hv;
    if (t < w) offA[kb + t] = pos0;
    curk[t] = pos0;
    __syncthreads();
    for (int i = t; i < n; i += 512){
        u32 rc = rec[start + i];
        int local = (int)(rc >> 17);
        float alpha = evb[start + i] / s[local];
        int pos = atomicAdd(&curk[local], 1);
        sorted2[pos] = make_int2((int)(rc & 0x1FFFFu), __float_as_int(alpha));
    }
}

// ------------------------------------------------- fused aggregation + dual-GEMM + epilogue
// Wide-gather layout (r12 config — best found): 16 lanes per edge-row
// (16B/lane), 4 edges per wave-instruction, single-depth paired streams.
// (r13's 2-deep pipeline REGRESSED: VGPR 48->56 cost occupancy 53->42%.)
template<int BF>
__global__ __launch_bounds__(256) void agg_gemm_epi(
    const int* __restrict__ cnt, const int* __restrict__ offA, const int2* __restrict__ sorted2,
    const void* __restrict__ hk, const void* __restrict__ he, const void* __restrict__ hs,
    const u16* __restrict__ Wf,
    const float* __restrict__ kfc2w, const float* __restrict__ kfc2b,
    const float* __restrict__ kfc3w, const float* __restrict__ kfc3b,
    const float* __restrict__ efc1w, const float* __restrict__ efc1b,
    const float* __restrict__ efc2w, const float* __restrict__ efc2b,
    float* __restrict__ out)
{
    __shared__ u16 ldsC[16*136];
    __shared__ u16 ldsD[16*136];
    __shared__ float sred2[16], sred3[16], p2s[16], p3s[16];

    int bid = blockIdx.x;
    int wave = threadIdx.x >> 6, lane = threadIdx.x & 63;
    int g = lane >> 4, s = lane & 15;
    int kind, node0, keyC, keyD;
    const void *hC, *hD, *Aseg;
    const u16 *wc, *wd;
    const float *w2, *b2, *w3, *b3;
    float* outp;
    if (bid < KN_B){
        kind=0; node0 = bid*16;
        keyC = KB1 + node0; keyD = KB2 + node0;
        hC = hk; hD = he; Aseg = hk;
        wc = Wf; wd = Wf + 16384;
        w2=kfc2w; b2=kfc2b; w3=kfc3w; b3=kfc3b;
        outp = out;
    } else if (bid < KN_B + EX_B){
        kind=0; node0 = (bid - KN_B)*16;
        keyC = KB3 + node0; keyD = KB5 + node0;
        hC = hk; hD = hs; Aseg = he;
        wc = Wf + 2*16384; wd = Wf + 4*16384;
        w2=efc1w; b2=efc1b; w3=efc2w; b3=efc2b;
        outp = out + (size_t)N_K*128;
    } else {
        kind=1; node0 = (bid - KN_B - EX_B)*16;
        keyC = KB4 + node0; keyD = 0;
        hC = he; hD = nullptr; Aseg = hs;
        wc = Wf + 3*16384; wd = nullptr;
        w2=nullptr; b2=nullptr; w3=nullptr; b3=nullptr;
        outp = out + (size_t)(N_K + N_E)*128;
    }

    // ---- aggregation into LDS: paired rows, 4-edge-wide chunks ----
    int rpw = (kind == 0) ? 8 : 4;
    for (int rr = 0; rr < rpw; rr += 2){
        int cA = wave*rpw + rr;                 // even -> pair stays in one seg
        int seg = cA >> 4, ndA = cA & 15;
        int keyA = (seg == 0 ? keyC : keyD) + ndA;
        const u16* hb = (const u16*)(seg == 0 ? hC : hD);
        const float4* hf = (const float4*)(seg == 0 ? hC : hD);
        int degA = cnt[keyA],     startA = offA[keyA];
        int degB = cnt[keyA + 1], startB = offA[keyA + 1];
        float aA8[8], aB8[8];
        #pragma unroll
        for (int k = 0; k < 8; ++k){ aA8[k] = 0.f; aB8[k] = 0.f; }

        auto chunk = [&](const int2* sp, float* acc){
            int2 w = sp[g];
            float al = __int_as_float(w.y);
            if (BF){
                uint4 hv = *(const uint4*)(hb + (size_t)w.x*128 + s*8);
                acc[0] = fmaf(al, bf2f((u16)hv.x), acc[0]);
                acc[1] = fmaf(al, bf2f((u16)(hv.x>>16)), acc[1]);
                acc[2] = fmaf(al, bf2f((u16)hv.y), acc[2]);
                acc[3] = fmaf(al, bf2f((u16)(hv.y>>16)), acc[3]);
                acc[4] = fmaf(al, bf2f((u16)hv.z), acc[4]);
                acc[5] = fmaf(al, bf2f((u16)(hv.z>>16)), acc[5]);
                acc[6] = fmaf(al, bf2f((u16)hv.w), acc[6]);
                acc[7] = fmaf(al, bf2f((u16)(hv.w>>16)), acc[7]);
            } else {
                const float4* rp = hf + (size_t)w.x*32 + s*2;
                float4 p0 = rp[0], p1 = rp[1];
                acc[0] = fmaf(al, p0.x, acc[0]); acc[1] = fmaf(al, p0.y, acc[1]);
                acc[2] = fmaf(al, p0.z, acc[2]); acc[3] = fmaf(al, p0.w, acc[3]);
                acc[4] = fmaf(al, p1.x, acc[4]); acc[5] = fmaf(al, p1.y, acc[5]);
                acc[6] = fmaf(al, p1.z, acc[6]); acc[7] = fmaf(al, p1.w, acc[7]);
            }
        };

        int iA = 0, iB = 0;
        while (iA + 4 <= degA && iB + 4 <= degB){
            chunk(sorted2 + startA + iA, aA8);
            chunk(sorted2 + startB + iB, aB8);
            iA += 4; iB += 4;
        }
        for (; iA + 4 <= degA; iA += 4) chunk(sorted2 + startA + iA, aA8);
        for (; iB + 4 <= degB; iB += 4) chunk(sorted2 + startB + iB, aB8);
        int remA = degA - iA;
        if (g < remA) chunk(sorted2 + startA + iA, aA8);   // per-group predicated tail
        int remB = degB - iB;
        if (g < remB) chunk(sorted2 + startB + iB, aB8);

        // merge the 4 lane-groups (same columns, disjoint edge subsets)
        #pragma unroll
        for (int k = 0; k < 8; ++k){
            aA8[k] += __shfl_xor(aA8[k], 16); aA8[k] += __shfl_xor(aA8[k], 32);
            aB8[k] += __shfl_xor(aB8[k], 16); aB8[k] += __shfl_xor(aB8[k], 32);
        }
        u16* ldsSeg = (seg == 0 ? ldsC : ldsD);
        if (lane < 16){
            u32 p0 = (u32)f2bf(aA8[0]) | ((u32)f2bf(aA8[1]) << 16);
            u32 p1 = (u32)f2bf(aA8[2]) | ((u32)f2bf(aA8[3]) << 16);
            u32 p2 = (u32)f2bf(aA8[4]) | ((u32)f2bf(aA8[5]) << 16);
            u32 p3 = (u32)f2bf(aA8[6]) | ((u32)f2bf(aA8[7]) << 16);
            *(uint4*)(ldsSeg + ndA*136 + lane*8) = make_uint4(p0,p1,p2,p3);
            u32 q0 = (u32)f2bf(aB8[0]) | ((u32)f2bf(aB8[1]) << 16);
            u32 q1 = (u32)f2bf(aB8[2]) | ((u32)f2bf(aB8[3]) << 16);
            u32 q2 = (u32)f2bf(aB8[4]) | ((u32)f2bf(aB8[5]) << 16);
            u32 q3 = (u32)f2bf(aB8[6]) | ((u32)f2bf(aB8[7]) << 16);
            *(uint4*)(ldsSeg + (ndA+1)*136 + lane*8) = make_uint4(q0,q1,q2,q3);
        }
    }
    if (threadIdx.x < 16){ sred2[threadIdx.x] = 0.f; sred3[threadIdx.x] = 0.f; }
    __syncthreads();

    // ---- GEMM phase: wave handles ct = 2*wave, 2*wave+1 ----
    int colb = lane & 15, rlo = (lane >> 4)*4;
    const float* Af = (const float*)Aseg;
    const u16*   Ab = (const u16*)Aseg;

    bf16x8 afC[4];
    #pragma unroll
    for (int ks = 0; ks < 4; ++ks)
        afC[ks] = *(const bf16x8*)(ldsC + (lane & 15)*136 + ks*32 + (lane >> 4)*8);
    f32x4 accC[2];
    accC[0] = (f32x4){0.f,0.f,0.f,0.f}; accC[1] = (f32x4){0.f,0.f,0.f,0.f};
    #pragma unroll
    for (int ci = 0; ci < 2; ++ci){
        int ct = wave*2 + ci;
        #pragma unroll
        for (int ks = 0; ks < 4; ++ks){
            bf16x8 bfr = *(const bf16x8*)(wc + ((ct*4+ks)*64 + lane)*8);
            accC[ci] = __builtin_amdgcn_mfma_f32_16x16x32_bf16(afC[ks], bfr, accC[ci], 0, 0, 0);
        }
    }

    if (kind == 1){
        #pragma unroll
        for (int ci = 0; ci < 2; ++ci){
            int ct = wave*2 + ci;
            #pragma unroll
            for (int j = 0; j < 4; ++j){
                size_t idx = (size_t)(node0 + rlo + j)*128 + ct*16 + colb;
                float av = BF ? bf2f(Ab[idx]) : Af[idx];
                outp[idx] = accC[ci][j] + av;
            }
        }
        return;
    }

    bf16x8 afD[4];
    #pragma unroll
    for (int ks = 0; ks < 4; ++ks)
        afD[ks] = *(const bf16x8*)(ldsD + (lane & 15)*136 + ks*32 + (lane >> 4)*8);
    f32x4 accD[2];
    accD[0] = (f32x4){0.f,0.f,0.f,0.f}; accD[1] = (f32x4){0.f,0.f,0.f,0.f};
    #pragma unroll
    for (int ci = 0; ci < 2; ++ci){
        int ct = wave*2 + ci;
        #pragma unroll
        for (int ks = 0; ks < 4; ++ks){
            bf16x8 bfr = *(const bf16x8*)(wd + ((ct*4+ks)*64 + lane)*8);
            accD[ci] = __builtin_amdgcn_mfma_f32_16x16x32_bf16(afD[ks], bfr, accD[ci], 0, 0, 0);
        }
    }

    float aA[2][4];
    float s2p[4] = {0.f,0.f,0.f,0.f}, s3p[4] = {0.f,0.f,0.f,0.f};
    #pragma unroll
    for (int ci = 0; ci < 2; ++ci){
        int ct = wave*2 + ci;
        float w2l = w2[ct*16 + colb], w2h = w2[128 + ct*16 + colb];
        float w3l = w3[ct*16 + colb], w3h = w3[128 + ct*16 + colb];
        #pragma unroll
        for (int j = 0; j < 4; ++j){
            size_t idx = (size_t)(node0 + rlo + j)*128 + ct*16 + colb;
            float av = BF ? bf2f(Ab[idx]) : Af[idx];
            aA[ci][j] = av;
            s2p[j] = fmaf(av, w2l, fmaf(accC[ci][j], w2h, s2p[j]));
            s3p[j] = fmaf(av, w3l, fmaf(accD[ci][j], w3h, s3p[j]));
        }
    }
    #pragma unroll
    for (int m = 8; m; m >>= 1)
        #pragma unroll
        for (int j = 0; j < 4; ++j){
            s2p[j] += __shfl_xor(s2p[j], m);
            s3p[j] += __shfl_xor(s3p[j], m);
        }
    if (colb == 0){
        #pragma unroll
        for (int j = 0; j < 4; ++j){
            atomicAdd(&sred2[rlo + j], s2p[j]);
            atomicAdd(&sred3[rlo + j], s3p[j]);
        }
    }
    __syncthreads();
    if (threadIdx.x < 16){
        float s2 = sred2[threadIdx.x] + b2[0];
        float s3 = sred3[threadIdx.x] + b3[0];
        float mx = fmaxf(s2, s3);
        float e2 = __expf(s2 - mx), e3 = __expf(s3 - mx);
        float inv = 1.f/(e2 + e3);
        p2s[threadIdx.x] = e2*inv;
        p3s[threadIdx.x] = e3*inv;
    }
    __syncthreads();
    #pragma unroll
    for (int ci = 0; ci < 2; ++ci){
        int ct = wave*2 + ci;
        #pragma unroll
        for (int j = 0; j < 4; ++j){
            int row = rlo + j;
            size_t idx = (size_t)(node0 + row)*128 + ct*16 + colb;
            outp[idx] = aA[ci][j] + p2s[row]*accC[ci][j] + p3s[row]*accD[ci][j];
        }
    }
}

extern "C" void kernel_launch(void* const* d_in, const int* in_sizes, int n_in,
                              void* d_out, int out_size, void* d_ws, size_t ws_size,
                              hipStream_t stream)
{
    (void)in_sizes; (void)n_in; (void)out_size;
    const float* kn   = (const float*)d_in[0];
    const float* exer = (const float*)d_in[1];
    const float* stu  = (const float*)d_in[2];
    const int* und_src = (const int*)d_in[3];
    const int* und_dst = (const int*)d_in[4];
    const int* ek_src  = (const int*)d_in[5];
    const int* ek_dst  = (const int*)d_in[6];
    const int* eu_src  = (const int*)d_in[7];
    const int* eu_dst  = (const int*)d_in[8];
    const float* W_und = (const float*)d_in[9];  const float* a_und = (const float*)d_in[10];
    const float* W_ek  = (const float*)d_in[11]; const float* a_ek  = (const float*)d_in[12];
    const float* W_ke  = (const float*)d_in[13]; const float* a_ke  = (const float*)d_in[14];
    const float* W_eu  = (const float*)d_in[15]; const float* a_eu  = (const float*)d_in[16];
    const float* W_ue  = (const float*)d_in[17]; const float* a_ue  = (const float*)d_in[18];
    const float* kfc2w = (const float*)d_in[19]; const float* kfc2b = (const float*)d_in[20];
    const float* kfc3w = (const float*)d_in[21]; const float* kfc3b = (const float*)d_in[22];
    const float* efc1w = (const float*)d_in[23]; const float* efc1b = (const float*)d_in[24];
    const float* efc2w = (const float*)d_in[25]; const float* efc2b = (const float*)d_in[26];

    char* base = (char*)d_ws;
    size_t off_b = 0;
    auto alloc = [&](size_t bytes)->char*{
        char* p = base + off_b;
        off_b += (bytes + 255) & ~(size_t)255;
        return p;
    };
    float* vecs = (float*)alloc(1280*4);
    u16*   Wf   = (u16*)  alloc(5*16384*2);
    float* el1 = (float*)alloc(N_K*4);
    float* el2 = (float*)alloc(N_E*4);
    float* el3 = (float*)alloc(N_K*4);
    float* el4 = (float*)alloc(N_E*4);
    float* el5 = (float*)alloc(N_U*4);
    float* erc = (float*)alloc((size_t)N_TOT*4);
    int* cnt  = (int*)alloc((size_t)N_TOT*4);
    int* offA = (int*)alloc((size_t)N_TOT*4);
    int* btot = (int*)alloc(NBKT*4);
    int* bbase= (int*)alloc(NBKT*4);
    int* hist = (int*)alloc((size_t)NBKT*APAD*4);    // 3.2 MB
    u32* rec  = (u32*)alloc((size_t)E_TOT*4);        // {src | local<<17} packed
    float* evb = (float*)alloc((size_t)E_TOT*4);
    int2* sorted2 = (int2*)alloc((size_t)E_TOT*8);   // {src, alpha}
    u16* knb   = (u16*)alloc((size_t)N_K*128*2);
    u16* exerb = (u16*)alloc((size_t)N_E*128*2);
    u16* stub  = (u16*)alloc((size_t)N_U*128*2);
    size_t need_bf = off_b;
    bool useBF = (ws_size >= need_bf);
    float* out = (float*)d_out;

    prep_w<<<360,256,0,stream>>>(W_und,W_ek,W_ke,W_eu,W_ue, a_und,a_ek,a_ke,a_eu,a_ue, vecs, Wf);

    if (useBF)
        conv_all<1><<<(170000+3)/4,256,0,stream>>>(kn, exer, stu, knb, exerb, stub, vecs,
                                                   el1, el2, el3, el4, el5, erc);
    else
        conv_all<0><<<(170000+3)/4,256,0,stream>>>(kn, exer, stu, knb, exerb, stub, vecs,
                                                   el1, el2, el3, el4, el5, erc);

    bkt_hist<<<NBLKA,256,0,stream>>>(und_dst, ek_src, ek_dst, eu_src, eu_dst, hist);
    bkt_scan1<<<NBKT,512,0,stream>>>(hist, btot);
    bkt_scan2<<<1,1024,0,stream>>>(btot, bbase);
    bkt_scatter<<<NBLKA,256,0,stream>>>(und_src, und_dst, ek_src, ek_dst, eu_src, eu_dst,
                                        hist, bbase, rec);
    bkt_finalize<<<NBKT,512,0,stream>>>(rec, bbase, btot, erc,
                                        el1, el2, el3, el4, el5, evb,
                                        cnt, offA, sorted2);

    if (useBF){
        agg_gemm_epi<1><<<KN_B+EX_B+ST_B,256,0,stream>>>(cnt, offA, sorted2,
            knb, exerb, stub, Wf,
            kfc2w,kfc2b,kfc3w,kfc3b, efc1w,efc1b,efc2w,efc2b, out);
    } else {
        agg_gemm_epi<0><<<KN_B+EX_B+ST_B,256,0,stream>>>(cnt, offA, sorted2,
            kn, exer, stu, Wf,
            kfc2w,kfc2b,kfc3w,kfc3b, efc1w,efc1b,efc2w,efc2b, out);
    }
}